// Round 4
// baseline (427.065 us; speedup 1.0000x reference)
//
#include <hip/hip_runtime.h>
#include <float.h>
#include <math.h>

// Problem constants (from reference setup_inputs)
#define LQ   512
#define LL   4096      // key length
#define DD   64        // d_qk == d_v
#define KEEP 32        // MAX_SET_SIZE
#define NB   8         // batches
#define NROWS (NB * LQ)    // 4096 flat query rows
#define LW   (LL / 32)     // 128 packed words per row

// K1 tiling
#define RT    32           // query rows per block
#define NLC   8            // l-chunks per row
#define LC    (LL / NLC)   // 512
#define LSP   128          // l's per staging round
#define NPAIR (LC / LSP)   // 4

// ---- ws layout (floats) -----------------------------------------------------
// ck : [NROWS][NLC][KEEP] uint  candidate keys   4.19 MB
// ci : [NROWS][NLC][KEEP] int   candidate idx    4.19 MB
// VT : [NB][DD][LL] bf16                          4.19 MB
// pm : [NROWS][LW] uint  bit-packed mask          2.10 MB
#define WS_CI    (NROWS * NLC * KEEP)            // 1,048,576
#define WS_VT    (2 * NROWS * NLC * KEEP)        // 2,097,152
#define WS_PM    (WS_VT + (NB * DD * LL) / 2)    // 3,145,728
#define WS_TOTAL (WS_PM + NROWS * LW)            // 3,670,016 floats = 14.68 MB

#define MASKED_KEY 0x00800000u              // order-key of -FLT_MAX

typedef short  bf16x8 __attribute__((ext_vector_type(8)));
typedef float  f32x4  __attribute__((ext_vector_type(4)));

__device__ __forceinline__ float dot4(float4 a, float4 b) {
    return a.x * b.x + a.y * b.y + a.z * b.z + a.w * b.w;
}
__device__ __forceinline__ unsigned short f2bf(float f) {
    unsigned int u = __float_as_uint(f);
    return (unsigned short)((u + 0x7FFFu + ((u >> 16) & 1u)) >> 16);   // RNE
}
__device__ __forceinline__ unsigned int f2key(float f) {
    unsigned int u = __float_as_uint(f);
    return ((int)u < 0) ? ~u : (u | 0x80000000u);
}

// ============================================================================
// P-1: bit-pack mask int32 -> pm (67 MB -> 2.1 MB). Ballot-based: one wave
// packs 64 bools per iteration; coalesced 256 B loads; LDS-staged word store.
// ============================================================================
__global__ __launch_bounds__(256) void k_pack(
    const int* __restrict__ mask, unsigned int* __restrict__ pm)
{
    __shared__ unsigned int wbuf[4][64];
    const int t = threadIdx.x, wave = t >> 6, lane = t & 63;
    const size_t gw = (size_t)blockIdx.x * 4 + wave;   // 8192 waves total
    const int* src = mask + gw * 2048;
    #pragma unroll
    for (int i = 0; i < 32; ++i) {
        unsigned long long b = __ballot(src[i * 64 + lane] != 0);
        if (lane == 0) wbuf[wave][2 * i]     = (unsigned int)b;
        if (lane == 1) wbuf[wave][2 * i + 1] = (unsigned int)(b >> 32);
    }
    __asm__ volatile("s_waitcnt lgkmcnt(0)" ::: "memory");
    pm[gw * 64 + lane] = wbuf[wave][lane];
}

// ============================================================================
// P0: v[b][l][d] fp32 -> VT[b][d][l] bf16 (LDS tile transpose). 3 MB traffic.
// ============================================================================
#define TP_LB 256
__global__ __launch_bounds__(256) void k_vt(
    const float* __restrict__ v, unsigned short* __restrict__ vt)
{
    __shared__ unsigned short tile[DD][TP_LB + 8];   // +8 ushorts: bank de-phase
    const int t  = threadIdx.x;
    const int b  = blockIdx.x >> 4;                  // 16 blocks per batch
    const int l0 = (blockIdx.x & 15) * TP_LB;

    const float4* vg = reinterpret_cast<const float4*>(v + ((size_t)b * LL + l0) * DD);
    #pragma unroll
    for (int i = 0; i < 16; ++i) {
        int j = t + 256 * i;                         // f4 index: l = j>>4, dq = (j&15)*4
        float4 f = vg[j];
        int l = j >> 4, dq = (j & 15) * 4;
        tile[dq + 0][l] = f2bf(f.x);
        tile[dq + 1][l] = f2bf(f.y);
        tile[dq + 2][l] = f2bf(f.z);
        tile[dq + 3][l] = f2bf(f.w);
    }
    __syncthreads();
    const int d = t >> 2, seg = t & 3;               // 64 ushorts per thread
    const uint4* src = reinterpret_cast<const uint4*>(&tile[d][seg * 64]);
    uint4* dst = reinterpret_cast<uint4*>(vt + ((size_t)b * DD + d) * LL + l0 + seg * 64);
    #pragma unroll
    for (int i = 0; i < 8; ++i) dst[i] = src[i];
}

// ============================================================================
// P1: masked mean via bf16 MFMA, now from the PACKED mask (2.1 MB not 67 MB).
// Block = 16 rows x all 64 d, 8 waves; wave w owns l-range [w*512, +512).
// Per iteration: one uint word (32 l's) per (row, chunk); afrag bits -> exact
// 0/1 bf16. Writes out[n][d] = sum_v / clip(count,1). K2 later ADDS context.
// ============================================================================
__global__ __launch_bounds__(512) void k_mean(
    const unsigned int* __restrict__ pm,
    const unsigned short* __restrict__ vt,
    float* __restrict__ out)
{
    __shared__ float sums[8][4][16][16];             // 32 KB
    __shared__ float cnt_s[8][16];

    const int t     = threadIdx.x;
    const int wave  = t >> 6;                        // 0..7
    const int lane  = t & 63;
    const int n0    = blockIdx.x * 16;
    const int b     = n0 / LQ;
    const int row_a = lane & 15;                     // MFMA m / B n index
    const int chunk = lane >> 4;                     // k-quad

    const unsigned int* prow = pm + (size_t)(n0 + row_a) * LW + wave * 16;
    const unsigned short* vbase = vt + (size_t)b * DD * LL + wave * 512 + chunk * 8;

    f32x4 acc[4];
    #pragma unroll
    for (int dt = 0; dt < 4; ++dt) acc[dt] = (f32x4){0.f, 0.f, 0.f, 0.f};
    int cnt = 0;

    #pragma unroll
    for (int it = 0; it < 16; ++it) {
        const unsigned int wbits = prow[it];
        const unsigned int byte  = (wbits >> (chunk * 8)) & 0xFFu;
        cnt += __popc(byte);
        unsigned int p[4];
        p[0] = ((byte & 1u)   ? 0x3F80u : 0u) | ((byte & 2u)   ? 0x3F800000u : 0u);
        p[1] = ((byte & 4u)   ? 0x3F80u : 0u) | ((byte & 8u)   ? 0x3F800000u : 0u);
        p[2] = ((byte & 16u)  ? 0x3F80u : 0u) | ((byte & 32u)  ? 0x3F800000u : 0u);
        p[3] = ((byte & 64u)  ? 0x3F80u : 0u) | ((byte & 128u) ? 0x3F800000u : 0u);
        bf16x8 afrag = *reinterpret_cast<bf16x8*>(p);
        const int l0 = it * 32;
        #pragma unroll
        for (int dt = 0; dt < 4; ++dt) {
            bf16x8 bfrag = *reinterpret_cast<const bf16x8*>(
                vbase + (size_t)(dt * 16 + row_a) * LL + l0);
            acc[dt] = __builtin_amdgcn_mfma_f32_16x16x32_bf16(afrag, bfrag, acc[dt], 0, 0, 0);
        }
    }
    cnt += __shfl_xor(cnt, 16);
    cnt += __shfl_xor(cnt, 32);                      // all lanes: count[row_a] (this l-range)
    if (lane < 16) cnt_s[wave][lane] = (float)cnt;
    #pragma unroll
    for (int dt = 0; dt < 4; ++dt)
        #pragma unroll
        for (int r = 0; r < 4; ++r)
            sums[wave][dt][chunk * 4 + r][row_a] = acc[dt][r];
    __syncthreads();

    // final: thread t -> d = t&63, rows rgrp*2..+1 (512 threads cover 16 rows)
    const int d = t & 63, rgrp = t >> 6;
    #pragma unroll
    for (int rr = 0; rr < 2; ++rr) {
        const int row = rgrp * 2 + rr;
        float s = 0.f, c = 0.f;
        #pragma unroll
        for (int w = 0; w < 8; ++w) {
            s += sums[w][d >> 4][row][d & 15];
            c += cnt_s[w][row];
        }
        if (c < 1.f) c = 1.f;
        out[(size_t)(n0 + row) * DD + d] = s / c;
    }
}

// ============================================================================
// K1: masked scores (fp32 VALU, exact) -> per-(row, 512-l-chunk) top-32
// candidates. Mask from PACKED bits (2 uint loads per row-stage, L2-hot).
// Bisection restructured bit-major: `for bit { for p }` -> the 8 rows'
// count chains at each bit are independent (ILP 8), vs R3's row-major
// nesting whose 8x32 serial ballot chain cost ~65 us.
// ============================================================================
__global__ __launch_bounds__(256)
__attribute__((amdgpu_waves_per_eu(2, 4)))
void k_scores(
    const float* __restrict__ q,
    const float* __restrict__ kmat,
    const unsigned int* __restrict__ pm,
    unsigned int* __restrict__ ck,
    int*          __restrict__ ci)
{
    __shared__ float4 Ss4[16 * LSP];                 // 32 KB: K^T [dc][l]

    const int t    = threadIdx.x;
    const int wave = t >> 6;
    const int lane = t & 63;
    const int rt   = blockIdx.x >> 3;                // 0..127
    const int lc   = blockIdx.x & (NLC - 1);         // 0..7 -> XCD = blockIdx%8
    const int n0   = rt * RT;
    const int b    = n0 / LQ;
    const int lbase = lc * LC;

    int qbase[8];
    #pragma unroll
    for (int p = 0; p < 8; ++p)
        qbase[p] = __builtin_amdgcn_readfirstlane((n0 + wave * 8 + p) * DD);

    const float4* kg = reinterpret_cast<const float4*>(kmat) + (size_t)b * LL * 16;

    unsigned int key[8][2 * NPAIR];                  // [p][s*2+half], fully static idx

    #pragma unroll
    for (int s = 0; s < NPAIR; ++s) {
        const int l0 = lbase + s * LSP;
        __syncthreads();                             // Ss free
        #pragma unroll
        for (int i = 0; i < 2; ++i)
            #pragma unroll
            for (int j = 0; j < 4; ++j)
                Ss4[(wave * 4 + j) * LSP + lane + 64 * i] =
                    kg[(size_t)(l0 + lane + 64 * i) * 16 + wave * 4 + j];
        __syncthreads();

        float acc0[8], acc1[8];
        #pragma unroll
        for (int p = 0; p < 8; ++p) { acc0[p] = 0.f; acc1[p] = 0.f; }
        #pragma unroll
        for (int dc = 0; dc < 16; ++dc) {
            float4 ka = Ss4[dc * LSP + lane];
            float4 kb = Ss4[dc * LSP + 64 + lane];
            #pragma unroll
            for (int p = 0; p < 8; ++p) {
                float4 q4 = *reinterpret_cast<const float4*>(q + qbase[p] + dc * 4);
                acc0[p] += dot4(ka, q4);
                acc1[p] += dot4(kb, q4);
            }
        }
        #pragma unroll
        for (int p = 0; p < 8; ++p) {
            const int r = n0 + wave * 8 + p;
            const unsigned int* prow = pm + (size_t)r * LW;
            unsigned int w0 = prow[(l0 >> 5) + (lane >> 5)];
            unsigned int w1 = prow[(l0 >> 5) + 2 + (lane >> 5)];
            int m0 = (w0 >> (lane & 31)) & 1;
            int m1 = (w1 >> (lane & 31)) & 1;
            key[p][2 * s]     = m0 ? f2key(acc0[p] * 0.125f) : MASKED_KEY;
            key[p][2 * s + 1] = m1 ? f2key(acc1[p] * 0.125f) : MASKED_KEY;
        }
    }

    // ---- per-row exact top-32: bit-major bisection (8 rows in flight) -------
    unsigned int T[8];
    #pragma unroll
    for (int p = 0; p < 8; ++p) T[p] = 0u;
    for (int bit = 31; bit >= 0; --bit) {
        #pragma unroll
        for (int p = 0; p < 8; ++p) {
            const unsigned int cand = T[p] | (1u << bit);
            int cnt = 0;
            #pragma unroll
            for (int e = 0; e < 2 * NPAIR; ++e)
                cnt += (int)__popcll(__ballot(key[p][e] >= cand));
            if (cnt >= KEEP) T[p] = cand;
        }
    }

    const unsigned long long lmask =
        (lane == 63) ? 0x7fffffffffffffffull : ((1ull << lane) - 1ull);
    #pragma unroll
    for (int p = 0; p < 8; ++p) {
        const int row = n0 + wave * 8 + p;
        const unsigned int Tp = T[p];
        const bool take_eq = (Tp != MASKED_KEY);
        unsigned int* ckr = ck + ((size_t)row * NLC + lc) * KEEP;
        int*          cir = ci + ((size_t)row * NLC + lc) * KEEP;
        int nsel = 0;
        #pragma unroll
        for (int e = 0; e < 2 * NPAIR; ++e) {
            unsigned long long bg = __ballot(key[p][e] > Tp);
            int pre = (int)__popcll(bg & lmask);
            if (key[p][e] > Tp) {
                ckr[nsel + pre] = key[p][e];
                cir[nsel + pre] = lbase + ((e >> 1) << 7) + ((e & 1) << 6) + lane;
            }
            nsel += (int)__popcll(bg);
        }
        if (take_eq) {
            int rem = KEEP - nsel;
            #pragma unroll
            for (int e = 0; e < 2 * NPAIR; ++e) {
                if (rem <= 0) break;                 // wave-uniform
                unsigned long long be = __ballot(key[p][e] == Tp);
                int pre = (int)__popcll(be & lmask);
                if (key[p][e] == Tp && pre < rem) {
                    ckr[nsel + pre] = Tp;
                    cir[nsel + pre] = lbase + ((e >> 1) << 7) + ((e & 1) << 6) + lane;
                }
                int c = (int)__popcll(be); if (c > rem) c = rem;
                nsel += c; rem -= c;
            }
        }
        if (lane >= nsel && lane < KEEP) { ckr[lane] = MASKED_KEY; cir[lane] = 0; }
    }
}

// ============================================================================
// K2: merge 8 chunk-candidate lists (256 pairs/row, 2 KB) -> exact global
// top-32 via 4-reg bisection, softmax, padded static gather; accumulates
// onto the mean already in out (written by k_mean). UNCHANGED (control).
// ============================================================================
__global__ __launch_bounds__(256) void k_select(
    const float* __restrict__ vmat,
    const unsigned int* __restrict__ ck,
    const int* __restrict__ ci,
    float*       __restrict__ out)
{
    __shared__ unsigned int selKey[4][KEEP];
    __shared__ int          selIdx[4][KEEP];
    __shared__ float        wsel[4][KEEP];
    __shared__ int          selCnt[4], eqCnt[4];

    const int t    = threadIdx.x;
    const int wave = t >> 6;
    const int lane = t & 63;
    const int row  = blockIdx.x * 4 + wave;
    const int b    = row / LQ;

    float o = out[(size_t)row * DD + lane];          // mean from k_mean (early load)

    // ---- load 256 candidates: 4 (key,idx) per lane --------------------------
    uint4 kk = reinterpret_cast<const uint4*>(ck + (size_t)row * (NLC * KEEP))[lane];
    int4  ii = reinterpret_cast<const int4*>(ci + (size_t)row * (NLC * KEEP))[lane];
    unsigned int key[4] = { kk.x, kk.y, kk.z, kk.w };
    int          idx[4] = { ii.x, ii.y, ii.z, ii.w };

    // ---- exact 32nd-largest key via 32-step bit bisection -------------------
    unsigned int T = 0u;
    for (int bit = 31; bit >= 0; --bit) {
        const unsigned int cand = T | (1u << bit);
        int cnt = 0;
        #pragma unroll
        for (int e = 0; e < 4; ++e)
            cnt += (int)__popcll(__ballot(key[e] >= cand));
        if (cnt >= KEEP) T = cand;
    }
    int cgt = 0;
    #pragma unroll
    for (int e = 0; e < 4; ++e)
        cgt += (int)__popcll(__ballot(key[e] > T));
    const unsigned int quota = (unsigned int)(KEEP - cgt);
    const bool take_eq = (T != MASKED_KEY);

    // ---- compact selected (key,idx) into LDS --------------------------------
    if (lane < KEEP) { wsel[wave][lane] = 0.f; selIdx[wave][lane] = 0; }
    if (lane == 0)   { selCnt[wave] = 0; eqCnt[wave] = 0; }
    __asm__ volatile("s_waitcnt lgkmcnt(0)" ::: "memory");
    #pragma unroll
    for (int e = 0; e < 4; ++e) {
        unsigned int k = key[e];
        if (k > T) {
            int slot = atomicAdd(&selCnt[wave], 1);
            selKey[wave][slot] = k;
            selIdx[wave][slot] = idx[e];
        } else if (take_eq && k == T) {
            int t2 = atomicAdd(&eqCnt[wave], 1);
            if (t2 < (int)quota) {
                int slot = atomicAdd(&selCnt[wave], 1);
                selKey[wave][slot] = k;
                selIdx[wave][slot] = idx[e];
            }
        }
    }
    __asm__ volatile("s_waitcnt lgkmcnt(0)" ::: "memory");
    const int S = selCnt[wave];

    // ---- softmax over selected + padded static gather -----------------------
    if (S > 0) {
        float vj = -FLT_MAX;
        if (lane < S) {
            unsigned int kk2 = selKey[wave][lane];
            unsigned int u = (kk2 & 0x80000000u) ? (kk2 ^ 0x80000000u) : ~kk2;
            vj = __uint_as_float(u);
        }
        float mx = vj;
        #pragma unroll
        for (int off = 1; off < 64; off <<= 1) mx = fmaxf(mx, __shfl_xor(mx, off));
        float e = (lane < S) ? expf(vj - mx) : 0.f;
        float sum = e;
        #pragma unroll
        for (int off = 1; off < 64; off <<= 1) sum += __shfl_xor(sum, off);
        if (lane < S) wsel[wave][lane] = e / sum;
        __asm__ volatile("s_waitcnt lgkmcnt(0)" ::: "memory");
        const float* vb = vmat + (size_t)b * LL * DD + lane;
        #pragma unroll
        for (int j = 0; j < KEEP; ++j) {
            float wj = wsel[wave][j];
            int   ij = selIdx[wave][j];
            o += wj * vb[(size_t)ij * DD];
        }
    }
    out[(size_t)row * DD + lane] = o;
}

// ============================================================================
// Fallback (proven round-1 monolith) in case ws_size < WS_TOTAL*4.
// ============================================================================
#define QT   2
#define NT   256
#define NTILES (LL / NT)

__global__ __launch_bounds__(NT, 4) void ga_fused_fb(
    const float* __restrict__ q, const float* __restrict__ kmat,
    const float* __restrict__ vmat, const int* __restrict__ mask,
    float* __restrict__ out)
{
    __shared__ float sc[QT][LL];
    __shared__ float q_s[QT][DD];
    __shared__ unsigned long long mbits[QT][LL / 64];
    __shared__ float redv[4][QT][DD];
    __shared__ float mean_s[QT][DD];
    __shared__ int   count_s[QT];
    __shared__ int   sel_idx[QT][KEEP];
    __shared__ float sel_val[QT][KEEP];
    __shared__ int   sel_cnt[QT];
    __shared__ float wred[4];
    __shared__ int   ired[4];
    __shared__ int   brk;
    __shared__ float wgt[QT][KEEP];

    const int t = threadIdx.x, wave = t >> 6, lane = t & 63;
    const int n0 = blockIdx.x * QT, b = n0 / LQ;

    if (t < QT) sel_cnt[t] = 0;
    if (t < QT * DD) q_s[t >> 6][t & 63] = q[(size_t)(n0 + (t >> 6)) * DD + (t & 63)];
    __syncthreads();

    const float4* q4_0 = reinterpret_cast<const float4*>(&q_s[0][0]);
    const float4* q4_1 = reinterpret_cast<const float4*>(&q_s[1][0]);
    for (int tile = 0; tile < NTILES; ++tile) {
        int l = tile * NT + t;
        const float4* kr = reinterpret_cast<const float4*>(kmat + (size_t)(b * LL + l) * DD);
        float d0 = 0.f, d1 = 0.f;
        #pragma unroll
        for (int i = 0; i < 16; ++i) {
            float4 kk = kr[i], qa = q4_0[i], qb = q4_1[i];
            d0 += kk.x * qa.x + kk.y * qa.y + kk.z * qa.z + kk.w * qa.w;
            d1 += kk.x * qb.x + kk.y * qb.y + kk.z * qb.z + kk.w * qb.w;
        }
        int mv0 = mask[(size_t)n0 * LL + l];
        int mv1 = mask[(size_t)(n0 + 1) * LL + l];
        unsigned long long b0 = __ballot(mv0 != 0);
        unsigned long long b1 = __ballot(mv1 != 0);
        if (lane == 0) { mbits[0][tile * 4 + wave] = b0; mbits[1][tile * 4 + wave] = b1; }
        sc[0][l] = mv0 ? d0 * 0.125f : -FLT_MAX;
        sc[1][l] = mv1 ? d1 * 0.125f : -FLT_MAX;
    }
    __syncthreads();

    if (wave < QT) {
        int c = (int)__popcll(mbits[wave][lane]);
        for (int off = 32; off >= 1; off >>= 1) c += __shfl_down(c, off);
        if (lane == 0) count_s[wave] = c;
    }
    {
        float acc0 = 0.f, acc1 = 0.f;
        const int g = wave, d = lane;
        for (int wi = 0; wi < LL / 64; ++wi) {
            unsigned long long w0 = mbits[0][wi], w1 = mbits[1][wi];
            const float* vp = vmat + (size_t)(b * LL + wi * 64 + g) * DD + d;
            #pragma unroll 4
            for (int ii = 0; ii < 16; ++ii) {
                int sh = g + 4 * ii;
                float vv = vp[(size_t)(4 * ii) * DD];
                if ((w0 >> sh) & 1ULL) acc0 += vv;
                if ((w1 >> sh) & 1ULL) acc1 += vv;
            }
        }
        redv[g][0][d] = acc0; redv[g][1][d] = acc1;
    }
    __syncthreads();
    if (t < QT * DD) {
        int qt = t >> 6, dd = t & 63;
        float s2 = redv[0][qt][dd] + redv[1][qt][dd] + redv[2][qt][dd] + redv[3][qt][dd];
        int c = count_s[qt]; if (c < 1) c = 1;
        mean_s[qt][dd] = s2 / (float)c;
    }
    __syncthreads();

    for (int qt = 0; qt < QT; ++qt) {
        for (int s = 0; s < KEEP; ++s) {
            float m = -FLT_MAX; int mi = LL;
            for (int j = 0; j < NTILES; ++j) {
                int l = j * NT + t;
                float val = sc[qt][l];
                if (val > m) { m = val; mi = l; }
            }
            for (int off = 32; off >= 1; off >>= 1) {
                float ov = __shfl_down(m, off);
                int   oi = __shfl_down(mi, off);
                if (ov > m || (ov == m && oi < mi)) { m = ov; mi = oi; }
            }
            if (lane == 0) { wred[wave] = m; ired[wave] = mi; }
            __syncthreads();
            if (t == 0) {
                float bv = wred[0]; int bi = ired[0];
                for (int w2 = 1; w2 < 4; ++w2) {
                    float ov = wred[w2]; int oi = ired[w2];
                    if (ov > bv || (ov == bv && oi < bi)) { bv = ov; bi = oi; }
                }
                if (bv > -FLT_MAX) {
                    sel_idx[qt][s] = bi; sel_val[qt][s] = bv; sel_cnt[qt] = s + 1;
                    sc[qt][bi] = -FLT_MAX; brk = 0;
                } else brk = 1;
            }
            __syncthreads();
            if (brk) break;
        }
    }

    if (wave < QT) {
        int qt = wave, S = sel_cnt[qt];
        if (S > 0) {
            float mx = sel_val[qt][0];
            float e = 0.f;
            if (lane < S) e = expf(sel_val[qt][lane] - mx);
            float ssum = e;
            for (int off = 32; off >= 1; off >>= 1) ssum += __shfl_xor(ssum, off);
            if (lane < S) wgt[qt][lane] = e / ssum;
        }
    }
    __syncthreads();
    if (wave < QT) {
        int qt = wave, S = sel_cnt[qt];
        float o = mean_s[qt][lane];
        for (int j = 0; j < S; ++j)
            o += wgt[qt][j] * vmat[(size_t)(b * LL + sel_idx[qt][j]) * DD + lane];
        out[(size_t)(n0 + qt) * DD + lane] = o;
    }
}

// ============================================================================
extern "C" void kernel_launch(void* const* d_in, const int* in_sizes, int n_in,
                              void* d_out, int out_size, void* d_ws, size_t ws_size,
                              hipStream_t stream) {
    const float* q    = (const float*)d_in[0];
    const float* kmat = (const float*)d_in[1];
    const float* vmat = (const float*)d_in[2];
    const int*   mask = (const int*)d_in[3];
    float* out = (float*)d_out;

    const size_t need = (size_t)WS_TOTAL * sizeof(float);   // 14.68 MB
    if (ws_size >= need) {
        float* ws = (float*)d_ws;
        unsigned int* ck = (unsigned int*)ws;
        int*          ci = (int*)(ws + WS_CI);
        unsigned short* vt = (unsigned short*)(ws + WS_VT);
        unsigned int* pm = (unsigned int*)(ws + WS_PM);
        hipLaunchKernelGGL(k_pack, dim3(NROWS * LL / (2048 * 4)), dim3(256), 0, stream,
                           mask, pm);
        hipLaunchKernelGGL(k_vt, dim3(NB * 16), dim3(256), 0, stream, vmat, vt);
        hipLaunchKernelGGL(k_scores, dim3((NROWS / RT) * NLC), dim3(256), 0, stream,
                           q, kmat, pm, ck, ci);
        hipLaunchKernelGGL(k_mean, dim3(NROWS / 16), dim3(512), 0, stream,
                           pm, vt, out);
        hipLaunchKernelGGL(k_select, dim3(NROWS / 4), dim3(256), 0, stream,
                           vmat, ck, ci, out);
    } else {
        hipLaunchKernelGGL(ga_fused_fb, dim3(NROWS / QT), dim3(NT), 0, stream,
                           q, kmat, vmat, mask, out);
    }
}

// Round 5
// 334.498 us; speedup vs baseline: 1.2767x; 1.2767x over previous
//
#include <hip/hip_runtime.h>
#include <float.h>
#include <math.h>

// Problem constants (from reference setup_inputs)
#define LQ   512
#define LL   4096      // key length
#define DD   64        // d_qk == d_v
#define KEEP 32        // MAX_SET_SIZE
#define NB   8         // batches
#define NROWS (NB * LQ)    // 4096 flat query rows

// K1 tiling
#define RT    32           // query rows per block
#define NLC   8            // l-chunks per row
#define LC    (LL / NLC)   // 512
#define LSP   128          // l's per staging round
#define NPAIR (LC / LSP)   // 4

// ---- ws layout --------------------------------------------------------------
// scores : [NROWS][LL] fp32                67.11 MB
// VT     : [NB][DD][LL] bf16                4.19 MB
#define WS_VT    (NROWS * LL)               // float offset of VT region
#define WS_TOTAL (WS_VT + (NB * DD * LL) / 2)   // 17,825,792 floats = 71.30 MB

#define MASKED_KEY 0x00800000u              // order-key of -FLT_MAX

typedef short  bf16x8 __attribute__((ext_vector_type(8)));
typedef float  f32x4  __attribute__((ext_vector_type(4)));

__device__ __forceinline__ float dot4(float4 a, float4 b) {
    return a.x * b.x + a.y * b.y + a.z * b.z + a.w * b.w;
}
__device__ __forceinline__ unsigned short f2bf(float f) {
    unsigned int u = __float_as_uint(f);
    return (unsigned short)((u + 0x7FFFu + ((u >> 16) & 1u)) >> 16);   // RNE
}
__device__ __forceinline__ unsigned int f2key(float f) {
    unsigned int u = __float_as_uint(f);
    return ((int)u < 0) ? ~u : (u | 0x80000000u);
}

// ============================================================================
// P0: v[b][l][d] fp32 -> VT[b][d][l] bf16 (LDS tile transpose). 3 MB traffic.
// ============================================================================
#define TP_LB 256
__global__ __launch_bounds__(256) void k_vt(
    const float* __restrict__ v, unsigned short* __restrict__ vt)
{
    __shared__ unsigned short tile[DD][TP_LB + 8];   // +8 ushorts: bank de-phase
    const int t  = threadIdx.x;
    const int b  = blockIdx.x >> 4;                  // 16 blocks per batch
    const int l0 = (blockIdx.x & 15) * TP_LB;

    const float4* vg = reinterpret_cast<const float4*>(v + ((size_t)b * LL + l0) * DD);
    #pragma unroll
    for (int i = 0; i < 16; ++i) {
        int j = t + 256 * i;                         // f4 index: l = j>>4, dq = (j&15)*4
        float4 f = vg[j];
        int l = j >> 4, dq = (j & 15) * 4;
        tile[dq + 0][l] = f2bf(f.x);
        tile[dq + 1][l] = f2bf(f.y);
        tile[dq + 2][l] = f2bf(f.z);
        tile[dq + 3][l] = f2bf(f.w);
    }
    __syncthreads();
    const int d = t >> 2, seg = t & 3;               // 64 ushorts per thread
    const uint4* src = reinterpret_cast<const uint4*>(&tile[d][seg * 64]);
    uint4* dst = reinterpret_cast<uint4*>(vt + ((size_t)b * DD + d) * LL + l0 + seg * 64);
    #pragma unroll
    for (int i = 0; i < 8; ++i) dst[i] = src[i];
}

// ============================================================================
// P1: masked mean via bf16 MFMA, v2: mask bits built IN-KERNEL from coalesced
// streaming loads + ballots (replaces R1-R3's scattered per-row int4 loads
// that made k_mean latency-bound ~100us). Block = 16 rows x all 64 d, 8
// waves; wave w owns l-range [w*512, +512):
//   phase 1: stream mask[16 rows][512 l] coalesced, ballot -> LDS bit-words
//   phase 2: MFMA with afrag built from LDS bits (A = exact 0/1 bf16),
//            bfrag = VT fragment (direct 16-B load), as in R4 (verified).
// Writes out[n][d] = sum_v / clip(count,1). K2 later ADDS its context.
// ============================================================================
__global__ __launch_bounds__(512) void k_mean(
    const int* __restrict__ mask,
    const unsigned short* __restrict__ vt,
    float* __restrict__ out)
{
    __shared__ unsigned int mb32[8][16][17];         // [wave][row][word] +pad 8.7 KB
    __shared__ float sums[8][4][16][16];             // 32 KB
    __shared__ float cnt_s[8][16];

    const int t     = threadIdx.x;
    const int wave  = t >> 6;                        // 0..7
    const int lane  = t & 63;
    const int n0    = blockIdx.x * 16;
    const int b     = n0 / LQ;
    const int row_a = lane & 15;                     // MFMA m / B n index
    const int chunk = lane >> 4;                     // k-quad
    const int lbase = wave * 512;

    // ---- phase 1: coalesced mask stream -> ballot bits ----------------------
    for (int r = 0; r < 16; ++r) {
        const int* mrow = mask + (size_t)(n0 + r) * LL + lbase;
        #pragma unroll
        for (int i = 0; i < 8; ++i) {
            unsigned long long bl = __ballot(mrow[i * 64 + lane] != 0);
            if (lane == 0) mb32[wave][r][2 * i]     = (unsigned int)bl;
            if (lane == 1) mb32[wave][r][2 * i + 1] = (unsigned int)(bl >> 32);
        }
    }
    __syncthreads();

    // ---- phase 2: MFMA off LDS bits ----------------------------------------
    const unsigned short* vbase = vt + (size_t)b * DD * LL + lbase + chunk * 8;

    f32x4 acc[4];
    #pragma unroll
    for (int dt = 0; dt < 4; ++dt) acc[dt] = (f32x4){0.f, 0.f, 0.f, 0.f};
    int cnt = 0;

    #pragma unroll
    for (int it = 0; it < 16; ++it) {
        const unsigned int wbits = mb32[wave][row_a][it];
        const unsigned int byte  = (wbits >> (chunk * 8)) & 0xFFu;
        cnt += __popc(byte);
        unsigned int p[4];
        p[0] = ((byte & 1u)   ? 0x3F80u : 0u) | ((byte & 2u)   ? 0x3F800000u : 0u);
        p[1] = ((byte & 4u)   ? 0x3F80u : 0u) | ((byte & 8u)   ? 0x3F800000u : 0u);
        p[2] = ((byte & 16u)  ? 0x3F80u : 0u) | ((byte & 32u)  ? 0x3F800000u : 0u);
        p[3] = ((byte & 64u)  ? 0x3F80u : 0u) | ((byte & 128u) ? 0x3F800000u : 0u);
        bf16x8 afrag = *reinterpret_cast<bf16x8*>(p);
        const int l0 = it * 32;
        #pragma unroll
        for (int dt = 0; dt < 4; ++dt) {
            bf16x8 bfrag = *reinterpret_cast<const bf16x8*>(
                vbase + (size_t)(dt * 16 + row_a) * LL + l0);
            acc[dt] = __builtin_amdgcn_mfma_f32_16x16x32_bf16(afrag, bfrag, acc[dt], 0, 0, 0);
        }
    }
    cnt += __shfl_xor(cnt, 16);
    cnt += __shfl_xor(cnt, 32);                      // all lanes: count[row_a] (this l-range)
    if (lane < 16) cnt_s[wave][lane] = (float)cnt;
    #pragma unroll
    for (int dt = 0; dt < 4; ++dt)
        #pragma unroll
        for (int r = 0; r < 4; ++r)
            sums[wave][dt][chunk * 4 + r][row_a] = acc[dt][r];
    __syncthreads();

    // final: thread t -> d = t&63, rows rgrp*2..+1 (512 threads cover 16 rows)
    const int d = t & 63, rgrp = t >> 6;
    #pragma unroll
    for (int rr = 0; rr < 2; ++rr) {
        const int row = rgrp * 2 + rr;
        float s = 0.f, c = 0.f;
        #pragma unroll
        for (int w = 0; w < 8; ++w) {
            s += sums[w][d >> 4][row][d & 15];
            c += cnt_s[w][row];
        }
        if (c < 1.f) c = 1.f;
        out[(size_t)(n0 + row) * DD + d] = s / c;
    }
}

// ============================================================================
// K1: masked scores -> ws (fp32 VALU — precision-critical for top-k).
// EXACT revert to the proven R1 form (112us, VGPR 52). Selection lives in
// k_select again — both in-k_scores variants (R3 row-major, R4 bit-major)
// regressed via serialized ballot/scalar chains + VGPR 116 occupancy loss.
// ============================================================================
__global__ __launch_bounds__(256)
__attribute__((amdgpu_waves_per_eu(2, 4)))
void k_scores(
    const float* __restrict__ q,
    const float* __restrict__ kmat,
    const int*   __restrict__ mask,
    float*       __restrict__ ws_sc)
{
    __shared__ float4 Ss4[16 * LSP];                 // 32 KB: K^T [dc][l]

    const int t    = threadIdx.x;
    const int wave = t >> 6;
    const int lane = t & 63;
    const int rt   = blockIdx.x >> 3;                // 0..127
    const int lc   = blockIdx.x & (NLC - 1);         // 0..7 -> XCD = blockIdx%8
    const int n0   = rt * RT;
    const int b    = n0 / LQ;
    const int lbase = lc * LC;

    int qbase[8];
    #pragma unroll
    for (int p = 0; p < 8; ++p)
        qbase[p] = __builtin_amdgcn_readfirstlane((n0 + wave * 8 + p) * DD);

    const float4* kg = reinterpret_cast<const float4*>(kmat) + (size_t)b * LL * 16;

    for (int s = 0; s < NPAIR; ++s) {
        const int l0 = lbase + s * LSP;
        __syncthreads();                             // Ss free
        #pragma unroll
        for (int i = 0; i < 2; ++i)
            #pragma unroll
            for (int j = 0; j < 4; ++j)
                Ss4[(wave * 4 + j) * LSP + lane + 64 * i] =
                    kg[(size_t)(l0 + lane + 64 * i) * 16 + wave * 4 + j];
        __syncthreads();

        float acc0[8], acc1[8];
        #pragma unroll
        for (int p = 0; p < 8; ++p) { acc0[p] = 0.f; acc1[p] = 0.f; }
        #pragma unroll
        for (int dc = 0; dc < 16; ++dc) {
            float4 ka = Ss4[dc * LSP + lane];
            float4 kb = Ss4[dc * LSP + 64 + lane];
            #pragma unroll
            for (int p = 0; p < 8; ++p) {
                float4 q4 = *reinterpret_cast<const float4*>(q + qbase[p] + dc * 4);
                acc0[p] += dot4(ka, q4);
                acc1[p] += dot4(kb, q4);
            }
        }
        #pragma unroll
        for (int p = 0; p < 8; ++p) {
            const int r = wave * 8 + p;
            int m0 = mask[(size_t)(n0 + r) * LL + l0 + lane];
            int m1 = mask[(size_t)(n0 + r) * LL + l0 + 64 + lane];
            ws_sc[(size_t)(n0 + r) * LL + l0 + lane]      = m0 ? acc0[p] * 0.125f : -FLT_MAX;
            ws_sc[(size_t)(n0 + r) * LL + l0 + 64 + lane] = m1 ? acc1[p] * 0.125f : -FLT_MAX;
        }
    }
}

// ============================================================================
// K2: per-wave exact top-32 over the full 4096-score row, v2 algorithm:
// 32-step bit bisection with PER-LANE VALU counting (c += (key>=cand), lane-
// parallel, throughput-bound) + one 6-step shfl_xor reduce per bit. Replaces
// the ballot+s_bcnt chains (serialized vcc->SALU, ~40cyc each) that cost
// 65-150us in R1-R4 regardless of which kernel hosted them.
// Then compaction/softmax/padded gather as proven; adds onto mean in out.
// ============================================================================
__global__ __launch_bounds__(256) void k_select(
    const float* __restrict__ vmat,
    const float* __restrict__ ws,
    float*       __restrict__ out)
{
    __shared__ unsigned int selKey[4][KEEP];
    __shared__ int          selIdx[4][KEEP];
    __shared__ float        wsel[4][KEEP];
    __shared__ int          selCnt[4], eqCnt[4];

    const int t    = threadIdx.x;
    const int wave = t >> 6;
    const int lane = t & 63;
    const int row  = blockIdx.x * 4 + wave;
    const int b    = row / LQ;

    float o = out[(size_t)row * DD + lane];          // mean from k_mean (early load)

    // ---- load row scores -> order-preserving uint keys (64 VGPRs) -----------
    unsigned int key[64];
    {
        const float4* sg = reinterpret_cast<const float4*>(ws) + (size_t)row * (LL / 4);
        #pragma unroll
        for (int i = 0; i < 16; ++i) {
            float4 f = sg[lane + 64 * i];
            key[4 * i + 0] = f2key(f.x);
            key[4 * i + 1] = f2key(f.y);
            key[4 * i + 2] = f2key(f.z);
            key[4 * i + 3] = f2key(f.w);
        }
    }

    // ---- exact 32nd-largest key: bisection w/ per-lane count ----------------
    unsigned int T = 0u;
    for (int bit = 31; bit >= 0; --bit) {
        const unsigned int cand = T | (1u << bit);
        int c = 0;
        #pragma unroll
        for (int e = 0; e < 64; ++e) c += (key[e] >= cand) ? 1 : 0;
        #pragma unroll
        for (int off = 1; off < 64; off <<= 1) c += __shfl_xor(c, off);
        if (c >= KEEP) T = cand;
    }
    int cgt = 0;                                     // #keys strictly greater than T
    #pragma unroll
    for (int e = 0; e < 64; ++e) cgt += (key[e] > T) ? 1 : 0;
    #pragma unroll
    for (int off = 1; off < 64; off <<= 1) cgt += __shfl_xor(cgt, off);
    const unsigned int quota = (unsigned int)(KEEP - cgt);   // how many ==T to take
    const bool take_eq = (T != MASKED_KEY);

    // ---- compact selected (key,idx) into LDS --------------------------------
    if (lane < KEEP) { wsel[wave][lane] = 0.f; selIdx[wave][lane] = 0; }
    if (lane == 0)   { selCnt[wave] = 0; eqCnt[wave] = 0; }
    __asm__ volatile("s_waitcnt lgkmcnt(0)" ::: "memory");
    #pragma unroll
    for (int e = 0; e < 64; ++e) {
        unsigned int k = key[e];
        if (k > T) {
            int slot = atomicAdd(&selCnt[wave], 1);
            selKey[wave][slot] = k;
            selIdx[wave][slot] = 256 * (e >> 2) + 4 * lane + (e & 3);
        } else if (take_eq && k == T) {
            int t2 = atomicAdd(&eqCnt[wave], 1);
            if (t2 < (int)quota) {
                int slot = atomicAdd(&selCnt[wave], 1);
                selKey[wave][slot] = k;
                selIdx[wave][slot] = 256 * (e >> 2) + 4 * lane + (e & 3);
            }
        }
    }
    __asm__ volatile("s_waitcnt lgkmcnt(0)" ::: "memory");
    const int S = selCnt[wave];

    // ---- softmax over selected + padded static gather -----------------------
    if (S > 0) {
        float vj = -FLT_MAX;
        if (lane < S) {
            unsigned int kk = selKey[wave][lane];
            unsigned int u = (kk & 0x80000000u) ? (kk ^ 0x80000000u) : ~kk;
            vj = __uint_as_float(u);
        }
        float mx = vj;
        #pragma unroll
        for (int off = 1; off < 64; off <<= 1) mx = fmaxf(mx, __shfl_xor(mx, off));
        float e = (lane < S) ? expf(vj - mx) : 0.f;
        float sum = e;
        #pragma unroll
        for (int off = 1; off < 64; off <<= 1) sum += __shfl_xor(sum, off);
        if (lane < S) wsel[wave][lane] = e / sum;
        __asm__ volatile("s_waitcnt lgkmcnt(0)" ::: "memory");
        const float* vb = vmat + (size_t)b * LL * DD + lane;
        #pragma unroll
        for (int j = 0; j < KEEP; ++j) {
            float wj = wsel[wave][j];
            int   ij = selIdx[wave][j];
            o += wj * vb[(size_t)ij * DD];
        }
    }
    out[(size_t)row * DD + lane] = o;
}

// ============================================================================
// Fallback (proven round-1 monolith) in case ws_size < WS_TOTAL*4.
// ============================================================================
#define QT   2
#define NT   256
#define NTILES (LL / NT)

__global__ __launch_bounds__(NT, 4) void ga_fused_fb(
    const float* __restrict__ q, const float* __restrict__ kmat,
    const float* __restrict__ vmat, const int* __restrict__ mask,
    float* __restrict__ out)
{
    __shared__ float sc[QT][LL];
    __shared__ float q_s[QT][DD];
    __shared__ unsigned long long mbits[QT][LL / 64];
    __shared__ float redv[4][QT][DD];
    __shared__ float mean_s[QT][DD];
    __shared__ int   count_s[QT];
    __shared__ int   sel_idx[QT][KEEP];
    __shared__ float sel_val[QT][KEEP];
    __shared__ int   sel_cnt[QT];
    __shared__ float wred[4];
    __shared__ int   ired[4];
    __shared__ int   brk;
    __shared__ float wgt[QT][KEEP];

    const int t = threadIdx.x, wave = t >> 6, lane = t & 63;
    const int n0 = blockIdx.x * QT, b = n0 / LQ;

    if (t < QT) sel_cnt[t] = 0;
    if (t < QT * DD) q_s[t >> 6][t & 63] = q[(size_t)(n0 + (t >> 6)) * DD + (t & 63)];
    __syncthreads();

    const float4* q4_0 = reinterpret_cast<const float4*>(&q_s[0][0]);
    const float4* q4_1 = reinterpret_cast<const float4*>(&q_s[1][0]);
    for (int tile = 0; tile < NTILES; ++tile) {
        int l = tile * NT + t;
        const float4* kr = reinterpret_cast<const float4*>(kmat + (size_t)(b * LL + l) * DD);
        float d0 = 0.f, d1 = 0.f;
        #pragma unroll
        for (int i = 0; i < 16; ++i) {
            float4 kk = kr[i], qa = q4_0[i], qb = q4_1[i];
            d0 += kk.x * qa.x + kk.y * qa.y + kk.z * qa.z + kk.w * qa.w;
            d1 += kk.x * qb.x + kk.y * qb.y + kk.z * qb.z + kk.w * qb.w;
        }
        int mv0 = mask[(size_t)n0 * LL + l];
        int mv1 = mask[(size_t)(n0 + 1) * LL + l];
        unsigned long long b0 = __ballot(mv0 != 0);
        unsigned long long b1 = __ballot(mv1 != 0);
        if (lane == 0) { mbits[0][tile * 4 + wave] = b0; mbits[1][tile * 4 + wave] = b1; }
        sc[0][l] = mv0 ? d0 * 0.125f : -FLT_MAX;
        sc[1][l] = mv1 ? d1 * 0.125f : -FLT_MAX;
    }
    __syncthreads();

    if (wave < QT) {
        int c = (int)__popcll(mbits[wave][lane]);
        for (int off = 32; off >= 1; off >>= 1) c += __shfl_down(c, off);
        if (lane == 0) count_s[wave] = c;
    }
    {
        float acc0 = 0.f, acc1 = 0.f;
        const int g = wave, d = lane;
        for (int wi = 0; wi < LL / 64; ++wi) {
            unsigned long long w0 = mbits[0][wi], w1 = mbits[1][wi];
            const float* vp = vmat + (size_t)(b * LL + wi * 64 + g) * DD + d;
            #pragma unroll 4
            for (int ii = 0; ii < 16; ++ii) {
                int sh = g + 4 * ii;
                float vv = vp[(size_t)(4 * ii) * DD];
                if ((w0 >> sh) & 1ULL) acc0 += vv;
                if ((w1 >> sh) & 1ULL) acc1 += vv;
            }
        }
        redv[g][0][d] = acc0; redv[g][1][d] = acc1;
    }
    __syncthreads();
    if (t < QT * DD) {
        int qt = t >> 6, dd = t & 63;
        float s2 = redv[0][qt][dd] + redv[1][qt][dd] + redv[2][qt][dd] + redv[3][qt][dd];
        int c = count_s[qt]; if (c < 1) c = 1;
        mean_s[qt][dd] = s2 / (float)c;
    }
    __syncthreads();

    for (int qt = 0; qt < QT; ++qt) {
        for (int s = 0; s < KEEP; ++s) {
            float m = -FLT_MAX; int mi = LL;
            for (int j = 0; j < NTILES; ++j) {
                int l = j * NT + t;
                float val = sc[qt][l];
                if (val > m) { m = val; mi = l; }
            }
            for (int off = 32; off >= 1; off >>= 1) {
                float ov = __shfl_down(m, off);
                int   oi = __shfl_down(mi, off);
                if (ov > m || (ov == m && oi < mi)) { m = ov; mi = oi; }
            }
            if (lane == 0) { wred[wave] = m; ired[wave] = mi; }
            __syncthreads();
            if (t == 0) {
                float bv = wred[0]; int bi = ired[0];
                for (int w2 = 1; w2 < 4; ++w2) {
                    float ov = wred[w2]; int oi = ired[w2];
                    if (ov > bv || (ov == bv && oi < bi)) { bv = ov; bi = oi; }
                }
                if (bv > -FLT_MAX) {
                    sel_idx[qt][s] = bi; sel_val[qt][s] = bv; sel_cnt[qt] = s + 1;
                    sc[qt][bi] = -FLT_MAX; brk = 0;
                } else brk = 1;
            }
            __syncthreads();
            if (brk) break;
        }
    }

    if (wave < QT) {
        int qt = wave, S = sel_cnt[qt];
        if (S > 0) {
            float mx = sel_val[qt][0];
            float e = 0.f;
            if (lane < S) e = expf(sel_val[qt][lane] - mx);
            float ssum = e;
            for (int off = 32; off >= 1; off >>= 1) ssum += __shfl_xor(ssum, off);
            if (lane < S) wgt[qt][lane] = e / ssum;
        }
    }
    __syncthreads();
    if (wave < QT) {
        int qt = wave, S = sel_cnt[qt];
        float o = mean_s[qt][lane];
        for (int j = 0; j < S; ++j)
            o += wgt[qt][j] * vmat[(size_t)(b * LL + sel_idx[qt][j]) * DD + lane];
        out[(size_t)(n0 + qt) * DD + lane] = o;
    }
}

// ============================================================================
extern "C" void kernel_launch(void* const* d_in, const int* in_sizes, int n_in,
                              void* d_out, int out_size, void* d_ws, size_t ws_size,
                              hipStream_t stream) {
    const float* q    = (const float*)d_in[0];
    const float* kmat = (const float*)d_in[1];
    const float* vmat = (const float*)d_in[2];
    const int*   mask = (const int*)d_in[3];
    float* out = (float*)d_out;

    const size_t need = (size_t)WS_TOTAL * sizeof(float);   // 71.30 MB (proven)
    if (ws_size >= need) {
        float* ws = (float*)d_ws;
        unsigned short* vt = (unsigned short*)(ws + WS_VT);
        hipLaunchKernelGGL(k_scores, dim3((NROWS / RT) * NLC), dim3(256), 0, stream,
                           q, kmat, mask, ws);
        hipLaunchKernelGGL(k_vt, dim3(NB * 16), dim3(256), 0, stream, vmat, vt);
        hipLaunchKernelGGL(k_mean, dim3(NROWS / 16), dim3(512), 0, stream,
                           mask, vt, out);
        hipLaunchKernelGGL(k_select, dim3(NROWS / 4), dim3(256), 0, stream,
                           vmat, ws, out);
    } else {
        hipLaunchKernelGGL(ga_fused_fb, dim3(NROWS / QT), dim3(NT), 0, stream,
                           q, kmat, vmat, mask, out);
    }
}

// Round 6
// 329.842 us; speedup vs baseline: 1.2948x; 1.0141x over previous
//
#include <hip/hip_runtime.h>
#include <float.h>
#include <math.h>

// Problem constants (from reference setup_inputs)
#define LQ   512
#define LL   4096      // key length
#define DD   64        // d_qk == d_v
#define KEEP 32        // MAX_SET_SIZE
#define NB   8         // batches
#define NROWS (NB * LQ)    // 4096 flat query rows

// K1 tiling
#define RT    32           // query rows per block
#define NLC   8            // l-chunks per row
#define LC    (LL / NLC)   // 512
#define LSP   128          // l's per staging round
#define NPAIR (LC / LSP)   // 4

// ---- ws layout --------------------------------------------------------------
// scores : [NROWS][LL] fp32                67.11 MB
// VT     : [NB][DD][LL] bf16                4.19 MB
#define WS_VT    (NROWS * LL)               // float offset of VT region
#define WS_TOTAL (WS_VT + (NB * DD * LL) / 2)   // 17,825,792 floats = 71.30 MB

#define MASKED_KEY 0x00800000u              // order-key of -FLT_MAX

typedef short  bf16x8 __attribute__((ext_vector_type(8)));
typedef float  f32x4  __attribute__((ext_vector_type(4)));

__device__ __forceinline__ float dot4(float4 a, float4 b) {
    return a.x * b.x + a.y * b.y + a.z * b.z + a.w * b.w;
}
__device__ __forceinline__ unsigned short f2bf(float f) {
    unsigned int u = __float_as_uint(f);
    return (unsigned short)((u + 0x7FFFu + ((u >> 16) & 1u)) >> 16);   // RNE
}
__device__ __forceinline__ unsigned int f2key(float f) {
    unsigned int u = __float_as_uint(f);
    return ((int)u < 0) ? ~u : (u | 0x80000000u);
}

// ============================================================================
// P0: v[b][l][d] fp32 -> VT[b][d][l] bf16 (LDS tile transpose). 3 MB traffic.
// UNCHANGED (control).
// ============================================================================
#define TP_LB 256
__global__ __launch_bounds__(256) void k_vt(
    const float* __restrict__ v, unsigned short* __restrict__ vt)
{
    __shared__ unsigned short tile[DD][TP_LB + 8];   // +8 ushorts: bank de-phase
    const int t  = threadIdx.x;
    const int b  = blockIdx.x >> 4;                  // 16 blocks per batch
    const int l0 = (blockIdx.x & 15) * TP_LB;

    const float4* vg = reinterpret_cast<const float4*>(v + ((size_t)b * LL + l0) * DD);
    #pragma unroll
    for (int i = 0; i < 16; ++i) {
        int j = t + 256 * i;                         // f4 index: l = j>>4, dq = (j&15)*4
        float4 f = vg[j];
        int l = j >> 4, dq = (j & 15) * 4;
        tile[dq + 0][l] = f2bf(f.x);
        tile[dq + 1][l] = f2bf(f.y);
        tile[dq + 2][l] = f2bf(f.z);
        tile[dq + 3][l] = f2bf(f.w);
    }
    __syncthreads();
    const int d = t >> 2, seg = t & 3;               // 64 ushorts per thread
    const uint4* src = reinterpret_cast<const uint4*>(&tile[d][seg * 64]);
    uint4* dst = reinterpret_cast<uint4*>(vt + ((size_t)b * DD + d) * LL + l0 + seg * 64);
    #pragma unroll
    for (int i = 0; i < 8; ++i) dst[i] = src[i];
}

// ============================================================================
// P1: masked mean via bf16 MFMA (v2, ballot-packed). UNCHANGED (control).
// ============================================================================
__global__ __launch_bounds__(512) void k_mean(
    const int* __restrict__ mask,
    const unsigned short* __restrict__ vt,
    float* __restrict__ out)
{
    __shared__ unsigned int mb32[8][16][17];         // [wave][row][word] +pad 8.7 KB
    __shared__ float sums[8][4][16][16];             // 32 KB
    __shared__ float cnt_s[8][16];

    const int t     = threadIdx.x;
    const int wave  = t >> 6;                        // 0..7
    const int lane  = t & 63;
    const int n0    = blockIdx.x * 16;
    const int b     = n0 / LQ;
    const int row_a = lane & 15;                     // MFMA m / B n index
    const int chunk = lane >> 4;                     // k-quad
    const int lbase = wave * 512;

    // ---- phase 1: coalesced mask stream -> ballot bits ----------------------
    for (int r = 0; r < 16; ++r) {
        const int* mrow = mask + (size_t)(n0 + r) * LL + lbase;
        #pragma unroll
        for (int i = 0; i < 8; ++i) {
            unsigned long long bl = __ballot(mrow[i * 64 + lane] != 0);
            if (lane == 0) mb32[wave][r][2 * i]     = (unsigned int)bl;
            if (lane == 1) mb32[wave][r][2 * i + 1] = (unsigned int)(bl >> 32);
        }
    }
    __syncthreads();

    // ---- phase 2: MFMA off LDS bits ----------------------------------------
    const unsigned short* vbase = vt + (size_t)b * DD * LL + lbase + chunk * 8;

    f32x4 acc[4];
    #pragma unroll
    for (int dt = 0; dt < 4; ++dt) acc[dt] = (f32x4){0.f, 0.f, 0.f, 0.f};
    int cnt = 0;

    #pragma unroll
    for (int it = 0; it < 16; ++it) {
        const unsigned int wbits = mb32[wave][row_a][it];
        const unsigned int byte  = (wbits >> (chunk * 8)) & 0xFFu;
        cnt += __popc(byte);
        unsigned int p[4];
        p[0] = ((byte & 1u)   ? 0x3F80u : 0u) | ((byte & 2u)   ? 0x3F800000u : 0u);
        p[1] = ((byte & 4u)   ? 0x3F80u : 0u) | ((byte & 8u)   ? 0x3F800000u : 0u);
        p[2] = ((byte & 16u)  ? 0x3F80u : 0u) | ((byte & 32u)  ? 0x3F800000u : 0u);
        p[3] = ((byte & 64u)  ? 0x3F80u : 0u) | ((byte & 128u) ? 0x3F800000u : 0u);
        bf16x8 afrag = *reinterpret_cast<bf16x8*>(p);
        const int l0 = it * 32;
        #pragma unroll
        for (int dt = 0; dt < 4; ++dt) {
            bf16x8 bfrag = *reinterpret_cast<const bf16x8*>(
                vbase + (size_t)(dt * 16 + row_a) * LL + l0);
            acc[dt] = __builtin_amdgcn_mfma_f32_16x16x32_bf16(afrag, bfrag, acc[dt], 0, 0, 0);
        }
    }
    cnt += __shfl_xor(cnt, 16);
    cnt += __shfl_xor(cnt, 32);                      // all lanes: count[row_a] (this l-range)
    if (lane < 16) cnt_s[wave][lane] = (float)cnt;
    #pragma unroll
    for (int dt = 0; dt < 4; ++dt)
        #pragma unroll
        for (int r = 0; r < 4; ++r)
            sums[wave][dt][chunk * 4 + r][row_a] = acc[dt][r];
    __syncthreads();

    // final: thread t -> d = t&63, rows rgrp*2..+1 (512 threads cover 16 rows)
    const int d = t & 63, rgrp = t >> 6;
    #pragma unroll
    for (int rr = 0; rr < 2; ++rr) {
        const int row = rgrp * 2 + rr;
        float s = 0.f, c = 0.f;
        #pragma unroll
        for (int w = 0; w < 8; ++w) {
            s += sums[w][d >> 4][row][d & 15];
            c += cnt_s[w][row];
        }
        if (c < 1.f) c = 1.f;
        out[(size_t)(n0 + row) * DD + d] = s / c;
    }
}

// ============================================================================
// K1: masked scores -> ws. UNCHANGED proven R1 form (112us control).
// ============================================================================
__global__ __launch_bounds__(256)
__attribute__((amdgpu_waves_per_eu(2, 4)))
void k_scores(
    const float* __restrict__ q,
    const float* __restrict__ kmat,
    const int*   __restrict__ mask,
    float*       __restrict__ ws_sc)
{
    __shared__ float4 Ss4[16 * LSP];                 // 32 KB: K^T [dc][l]

    const int t    = threadIdx.x;
    const int wave = t >> 6;
    const int lane = t & 63;
    const int rt   = blockIdx.x >> 3;                // 0..127
    const int lc   = blockIdx.x & (NLC - 1);         // 0..7 -> XCD = blockIdx%8
    const int n0   = rt * RT;
    const int b    = n0 / LQ;
    const int lbase = lc * LC;

    int qbase[8];
    #pragma unroll
    for (int p = 0; p < 8; ++p)
        qbase[p] = __builtin_amdgcn_readfirstlane((n0 + wave * 8 + p) * DD);

    const float4* kg = reinterpret_cast<const float4*>(kmat) + (size_t)b * LL * 16;

    for (int s = 0; s < NPAIR; ++s) {
        const int l0 = lbase + s * LSP;
        __syncthreads();                             // Ss free
        #pragma unroll
        for (int i = 0; i < 2; ++i)
            #pragma unroll
            for (int j = 0; j < 4; ++j)
                Ss4[(wave * 4 + j) * LSP + lane + 64 * i] =
                    kg[(size_t)(l0 + lane + 64 * i) * 16 + wave * 4 + j];
        __syncthreads();

        float acc0[8], acc1[8];
        #pragma unroll
        for (int p = 0; p < 8; ++p) { acc0[p] = 0.f; acc1[p] = 0.f; }
        #pragma unroll
        for (int dc = 0; dc < 16; ++dc) {
            float4 ka = Ss4[dc * LSP + lane];
            float4 kb = Ss4[dc * LSP + 64 + lane];
            #pragma unroll
            for (int p = 0; p < 8; ++p) {
                float4 q4 = *reinterpret_cast<const float4*>(q + qbase[p] + dc * 4);
                acc0[p] += dot4(ka, q4);
                acc1[p] += dot4(kb, q4);
            }
        }
        #pragma unroll
        for (int p = 0; p < 8; ++p) {
            const int r = wave * 8 + p;
            int m0 = mask[(size_t)(n0 + r) * LL + l0 + lane];
            int m1 = mask[(size_t)(n0 + r) * LL + l0 + 64 + lane];
            ws_sc[(size_t)(n0 + r) * LL + l0 + lane]      = m0 ? acc0[p] * 0.125f : -FLT_MAX;
            ws_sc[(size_t)(n0 + r) * LL + l0 + 64 + lane] = m1 ? acc1[p] * 0.125f : -FLT_MAX;
        }
    }
}

// ============================================================================
// K2 v6: ONE BLOCK PER ROW (4096 blocks -> up to 32 waves/CU, vs 16 before).
// Wave w owns score quarter [w*1024, +1024): burst 4x dwordx4 per lane
// (coalesced), exact per-quarter top-32 via bisection over 16 keys/lane
// (4x less serial work, ~50 VGPR). Wave 0 then merges the 4x32 candidates
// from LDS (global top-32 is contained in the union of quarter top-32s,
// tie multiplicity preserved), softmax + padded gather, adds mean from out.
// Mechanism targeted: ws read was pacing at ~1 TB/s (latency-bound, few
// outstanding reqs); 2x waves/CU + 4KB wave bursts + low VGPR fix that.
// ============================================================================
__global__ __launch_bounds__(256) void k_select(
    const float* __restrict__ vmat,
    const float* __restrict__ ws,
    float*       __restrict__ out)
{
    __shared__ unsigned int ckey[4][KEEP];
    __shared__ int          cidx[4][KEEP];
    __shared__ int          ccnt[4];
    __shared__ unsigned int selKey[KEEP];
    __shared__ int          selIdx[KEEP];
    __shared__ float        wsel[KEEP];
    __shared__ int          selCnt, eqCnt;

    const int t    = threadIdx.x;
    const int wave = t >> 6;
    const int lane = t & 63;
    const int row  = blockIdx.x;
    const int b    = row / LQ;

    // ---- per-wave: load 1024 scores of quarter `wave`, 16 keys/lane ---------
    unsigned int key[16];
    {
        const float4* sg = reinterpret_cast<const float4*>(ws)
                         + (size_t)row * (LL / 4) + wave * 256;
        #pragma unroll
        for (int i = 0; i < 4; ++i) {
            float4 f = sg[i * 64 + lane];
            key[4 * i + 0] = f2key(f.x);
            key[4 * i + 1] = f2key(f.y);
            key[4 * i + 2] = f2key(f.z);
            key[4 * i + 3] = f2key(f.w);
        }
    }
    // l-index of key[e]: wave*1024 + (e>>2)*256 + 4*lane + (e&3)

    // ---- per-wave exact 32nd-largest (bisection, per-lane VALU count) -------
    unsigned int T = 0u;
    for (int bit = 31; bit >= 0; --bit) {
        const unsigned int cand = T | (1u << bit);
        int c = 0;
        #pragma unroll
        for (int e = 0; e < 16; ++e) c += (key[e] >= cand) ? 1 : 0;
        #pragma unroll
        for (int off = 1; off < 64; off <<= 1) c += __shfl_xor(c, off);
        if (c >= KEEP) T = cand;
    }
    int cgt = 0;
    #pragma unroll
    for (int e = 0; e < 16; ++e) cgt += (key[e] > T) ? 1 : 0;
    #pragma unroll
    for (int off = 1; off < 64; off <<= 1) cgt += __shfl_xor(cgt, off);
    const int quota = KEEP - cgt;                    // #==T to take locally
    const bool take_eq = (T != MASKED_KEY);

    // ---- per-wave compaction of its quarter's top-32 into LDS ---------------
    if (lane == 0) ccnt[wave] = 0;
    if (lane < KEEP) ckey[wave][lane] = MASKED_KEY;  // pad
    if (t == 0) { selCnt = 0; eqCnt = 0; }
    __asm__ volatile("s_waitcnt lgkmcnt(0)" ::: "memory");
    int eqtaken = 0;
    #pragma unroll
    for (int e = 0; e < 16; ++e) {
        unsigned int k = key[e];
        bool sel = (k > T);
        if (!sel && take_eq && k == T) {
            // cheap local tie handling via LDS atomic on a per-wave counter
            sel = true;
        }
        if (sel) {
            if (k == T) {
                int t2 = atomicAdd(&ccnt[wave], 0);  // read current; see below
                (void)t2;
            }
        }
    }
    // NOTE: the loop above is folded into the simple atomic compaction below
    // (kept minimal & proven): >T always taken; ==T taken while quota lasts.
    #pragma unroll
    for (int e = 0; e < 16; ++e) {
        unsigned int k = key[e];
        if (k > T) {
            int slot = atomicAdd(&ccnt[wave], 1);
            ckey[wave][slot] = k;
            cidx[wave][slot] = wave * 1024 + 256 * (e >> 2) + 4 * lane + (e & 3);
        }
    }
    __asm__ volatile("s_waitcnt lgkmcnt(0)" ::: "memory");
    if (take_eq && quota > 0) {
        #pragma unroll
        for (int e = 0; e < 16; ++e) {
            unsigned int k = key[e];
            if (k == T) {
                int t2 = atomicAdd(&eqCnt, 0);       // dummy to order? not needed
                (void)t2;
                int slot = atomicAdd(&ccnt[wave], 1);
                if (slot < KEEP) {
                    ckey[wave][slot] = k;
                    cidx[wave][slot] = wave * 1024 + 256 * (e >> 2) + 4 * lane + (e & 3);
                }
            }
        }
    }
    (void)eqtaken;
    __syncthreads();

    // ---- wave 0: merge 128 candidates -> exact global top-32 ----------------
    if (wave == 0) {
        unsigned int k0 = ckey[lane >> 5][lane & 31];
        int          i0 = cidx[lane >> 5][lane & 31];
        unsigned int k1 = ckey[2 + (lane >> 5)][lane & 31];
        int          i1 = cidx[2 + (lane >> 5)][lane & 31];

        unsigned int Tg = 0u;
        for (int bit = 31; bit >= 0; --bit) {
            const unsigned int cand = Tg | (1u << bit);
            int c = (k0 >= cand) + (k1 >= cand);
            #pragma unroll
            for (int off = 1; off < 64; off <<= 1) c += __shfl_xor(c, off);
            if (c >= KEEP) Tg = cand;
        }
        int g = (k0 > Tg) + (k1 > Tg);
        #pragma unroll
        for (int off = 1; off < 64; off <<= 1) g += __shfl_xor(g, off);
        const int gq = KEEP - g;                     // #==Tg to take
        const bool geq = (Tg != MASKED_KEY);

        if (lane < KEEP) { wsel[lane] = 0.f; selIdx[lane] = 0; }
        __asm__ volatile("s_waitcnt lgkmcnt(0)" ::: "memory");
        // compact k0 then k1 (atomics, proven pattern)
        if (k0 > Tg) {
            int slot = atomicAdd(&selCnt, 1);
            selKey[slot] = k0; selIdx[slot] = i0;
        }
        if (k1 > Tg) {
            int slot = atomicAdd(&selCnt, 1);
            selKey[slot] = k1; selIdx[slot] = i1;
        }
        __asm__ volatile("s_waitcnt lgkmcnt(0)" ::: "memory");
        if (geq && gq > 0) {
            if (k0 == Tg) {
                int t2 = atomicAdd(&eqCnt, 1);
                if (t2 < gq) {
                    int slot = atomicAdd(&selCnt, 1);
                    selKey[slot] = k0; selIdx[slot] = i0;
                }
            }
            if (k1 == Tg) {
                int t2 = atomicAdd(&eqCnt, 1);
                if (t2 < gq) {
                    int slot = atomicAdd(&selCnt, 1);
                    selKey[slot] = k1; selIdx[slot] = i1;
                }
            }
        }
        __asm__ volatile("s_waitcnt lgkmcnt(0)" ::: "memory");
        const int S = selCnt;

        float o = out[(size_t)row * DD + lane];      // mean from k_mean
        if (S > 0) {
            float vj = -FLT_MAX;
            if (lane < S) {
                unsigned int kk = selKey[lane];
                unsigned int u = (kk & 0x80000000u) ? (kk ^ 0x80000000u) : ~kk;
                vj = __uint_as_float(u);
            }
            float mx = vj;
            #pragma unroll
            for (int off = 1; off < 64; off <<= 1) mx = fmaxf(mx, __shfl_xor(mx, off));
            float e = (lane < S) ? expf(vj - mx) : 0.f;
            float sum = e;
            #pragma unroll
            for (int off = 1; off < 64; off <<= 1) sum += __shfl_xor(sum, off);
            if (lane < S) wsel[lane] = e / sum;
            __asm__ volatile("s_waitcnt lgkmcnt(0)" ::: "memory");
            const float* vb = vmat + (size_t)b * LL * DD + lane;
            #pragma unroll
            for (int j = 0; j < KEEP; ++j) {
                float wj = wsel[j];
                int   ij = selIdx[j];
                o += wj * vb[(size_t)ij * DD];
            }
        }
        out[(size_t)row * DD + lane] = o;
    }
}

// ============================================================================
// Fallback (proven round-1 monolith) in case ws_size < WS_TOTAL*4.
// ============================================================================
#define QT   2
#define NT   256
#define NTILES (LL / NT)

__global__ __launch_bounds__(NT, 4) void ga_fused_fb(
    const float* __restrict__ q, const float* __restrict__ kmat,
    const float* __restrict__ vmat, const int* __restrict__ mask,
    float* __restrict__ out)
{
    __shared__ float sc[QT][LL];
    __shared__ float q_s[QT][DD];
    __shared__ unsigned long long mbits[QT][LL / 64];
    __shared__ float redv[4][QT][DD];
    __shared__ float mean_s[QT][DD];
    __shared__ int   count_s[QT];
    __shared__ int   sel_idx[QT][KEEP];
    __shared__ float sel_val[QT][KEEP];
    __shared__ int   sel_cnt[QT];
    __shared__ float wred[4];
    __shared__ int   ired[4];
    __shared__ int   brk;
    __shared__ float wgt[QT][KEEP];

    const int t = threadIdx.x, wave = t >> 6, lane = t & 63;
    const int n0 = blockIdx.x * QT, b = n0 / LQ;

    if (t < QT) sel_cnt[t] = 0;
    if (t < QT * DD) q_s[t >> 6][t & 63] = q[(size_t)(n0 + (t >> 6)) * DD + (t & 63)];
    __syncthreads();

    const float4* q4_0 = reinterpret_cast<const float4*>(&q_s[0][0]);
    const float4* q4_1 = reinterpret_cast<const float4*>(&q_s[1][0]);
    for (int tile = 0; tile < NTILES; ++tile) {
        int l = tile * NT + t;
        const float4* kr = reinterpret_cast<const float4*>(kmat + (size_t)(b * LL + l) * DD);
        float d0 = 0.f, d1 = 0.f;
        #pragma unroll
        for (int i = 0; i < 16; ++i) {
            float4 kk = kr[i], qa = q4_0[i], qb = q4_1[i];
            d0 += kk.x * qa.x + kk.y * qa.y + kk.z * qa.z + kk.w * qa.w;
            d1 += kk.x * qb.x + kk.y * qb.y + kk.z * qb.z + kk.w * qb.w;
        }
        int mv0 = mask[(size_t)n0 * LL + l];
        int mv1 = mask[(size_t)(n0 + 1) * LL + l];
        unsigned long long b0 = __ballot(mv0 != 0);
        unsigned long long b1 = __ballot(mv1 != 0);
        if (lane == 0) { mbits[0][tile * 4 + wave] = b0; mbits[1][tile * 4 + wave] = b1; }
        sc[0][l] = mv0 ? d0 * 0.125f : -FLT_MAX;
        sc[1][l] = mv1 ? d1 * 0.125f : -FLT_MAX;
    }
    __syncthreads();

    if (wave < QT) {
        int c = (int)__popcll(mbits[wave][lane]);
        for (int off = 32; off >= 1; off >>= 1) c += __shfl_down(c, off);
        if (lane == 0) count_s[wave] = c;
    }
    {
        float acc0 = 0.f, acc1 = 0.f;
        const int g = wave, d = lane;
        for (int wi = 0; wi < LL / 64; ++wi) {
            unsigned long long w0 = mbits[0][wi], w1 = mbits[1][wi];
            const float* vp = vmat + (size_t)(b * LL + wi * 64 + g) * DD + d;
            #pragma unroll 4
            for (int ii = 0; ii < 16; ++ii) {
                int sh = g + 4 * ii;
                float vv = vp[(size_t)(4 * ii) * DD];
                if ((w0 >> sh) & 1ULL) acc0 += vv;
                if ((w1 >> sh) & 1ULL) acc1 += vv;
            }
        }
        redv[g][0][d] = acc0; redv[g][1][d] = acc1;
    }
    __syncthreads();
    if (t < QT * DD) {
        int qt = t >> 6, dd = t & 63;
        float s2 = redv[0][qt][dd] + redv[1][qt][dd] + redv[2][qt][dd] + redv[3][qt][dd];
        int c = count_s[qt]; if (c < 1) c = 1;
        mean_s[qt][dd] = s2 / (float)c;
    }
    __syncthreads();

    for (int qt = 0; qt < QT; ++qt) {
        for (int s = 0; s < KEEP; ++s) {
            float m = -FLT_MAX; int mi = LL;
            for (int j = 0; j < NTILES; ++j) {
                int l = j * NT + t;
                float val = sc[qt][l];
                if (val > m) { m = val; mi = l; }
            }
            for (int off = 32; off >= 1; off >>= 1) {
                float ov = __shfl_down(m, off);
                int   oi = __shfl_down(mi, off);
                if (ov > m || (ov == m && oi < mi)) { m = ov; mi = oi; }
            }
            if (lane == 0) { wred[wave] = m; ired[wave] = mi; }
            __syncthreads();
            if (t == 0) {
                float bv = wred[0]; int bi = ired[0];
                for (int w2 = 1; w2 < 4; ++w2) {
                    float ov = wred[w2]; int oi = ired[w2];
                    if (ov > bv || (ov == bv && oi < bi)) { bv = ov; bi = oi; }
                }
                if (bv > -FLT_MAX) {
                    sel_idx[qt][s] = bi; sel_val[qt][s] = bv; sel_cnt[qt] = s + 1;
                    sc[qt][bi] = -FLT_MAX; brk = 0;
                } else brk = 1;
            }
            __syncthreads();
            if (brk) break;
        }
    }

    if (wave < QT) {
        int qt = wave, S = sel_cnt[qt];
        if (S > 0) {
            float mx = sel_val[qt][0];
            float e = 0.f;
            if (lane < S) e = expf(sel_val[qt][lane] - mx);
            float ssum = e;
            for (int off = 32; off >= 1; off >>= 1) ssum += __shfl_xor(ssum, off);
            if (lane < S) wgt[qt][lane] = e / ssum;
        }
    }
    __syncthreads();
    if (wave < QT) {
        int qt = wave, S = sel_cnt[qt];
        float o = mean_s[qt][lane];
        for (int j = 0; j < S; ++j)
            o += wgt[qt][j] * vmat[(size_t)(b * LL + sel_idx[qt][j]) * DD + lane];
        out[(size_t)(n0 + qt) * DD + lane] = o;
    }
}

// ============================================================================
extern "C" void kernel_launch(void* const* d_in, const int* in_sizes, int n_in,
                              void* d_out, int out_size, void* d_ws, size_t ws_size,
                              hipStream_t stream) {
    const float* q    = (const float*)d_in[0];
    const float* kmat = (const float*)d_in[1];
    const float* vmat = (const float*)d_in[2];
    const int*   mask = (const int*)d_in[3];
    float* out = (float*)d_out;

    const size_t need = (size_t)WS_TOTAL * sizeof(float);   // 71.30 MB (proven)
    if (ws_size >= need) {
        float* ws = (float*)d_ws;
        unsigned short* vt = (unsigned short*)(ws + WS_VT);
        hipLaunchKernelGGL(k_scores, dim3((NROWS / RT) * NLC), dim3(256), 0, stream,
                           q, kmat, mask, ws);
        hipLaunchKernelGGL(k_vt, dim3(NB * 16), dim3(256), 0, stream, vmat, vt);
        hipLaunchKernelGGL(k_mean, dim3(NROWS / 16), dim3(512), 0, stream,
                           mask, vt, out);
        hipLaunchKernelGGL(k_select, dim3(NROWS), dim3(256), 0, stream,
                           vmat, ws, out);
    } else {
        hipLaunchKernelGGL(ga_fused_fb, dim3(NROWS / QT), dim3(NT), 0, stream,
                           q, kmat, vmat, mask, out);
    }
}

// Round 7
// 324.263 us; speedup vs baseline: 1.3170x; 1.0172x over previous
//
#include <hip/hip_runtime.h>
#include <float.h>
#include <math.h>

// Problem constants (from reference setup_inputs)
#define LQ   512
#define LL   4096      // key length
#define DD   64        // d_qk == d_v
#define KEEP 32        // MAX_SET_SIZE
#define NB   8         // batches
#define NROWS (NB * LQ)    // 4096 flat query rows

// K1 tiling
#define RT    32           // query rows per block
#define NLC   8            // l-chunks per row
#define LC    (LL / NLC)   // 512
#define LSP   128          // l's per staging round
#define NPAIR (LC / LSP)   // 4

// ---- ws layout --------------------------------------------------------------
// scores : [NROWS][LL] fp32                67.11 MB
// VT     : [NB][DD][LL] bf16                4.19 MB
#define WS_VT    (NROWS * LL)               // float offset of VT region
#define WS_TOTAL (WS_VT + (NB * DD * LL) / 2)   // 17,825,792 floats = 71.30 MB

#define MASKED_KEY 0x00800000u              // order-key of -FLT_MAX

typedef short  bf16x8 __attribute__((ext_vector_type(8)));
typedef float  f32x4  __attribute__((ext_vector_type(4)));

__device__ __forceinline__ float dot4(float4 a, float4 b) {
    return a.x * b.x + a.y * b.y + a.z * b.z + a.w * b.w;
}
__device__ __forceinline__ unsigned short f2bf(float f) {
    unsigned int u = __float_as_uint(f);
    return (unsigned short)((u + 0x7FFFu + ((u >> 16) & 1u)) >> 16);   // RNE
}

// ============================================================================
// P0: v[b][l][d] fp32 -> VT[b][d][l] bf16 (LDS tile transpose). 3 MB traffic.
// UNCHANGED R1 form.
// ============================================================================
#define TP_LB 256
__global__ __launch_bounds__(256) void k_vt(
    const float* __restrict__ v, unsigned short* __restrict__ vt)
{
    __shared__ unsigned short tile[DD][TP_LB + 8];   // +8 ushorts: bank de-phase
    const int t  = threadIdx.x;
    const int b  = blockIdx.x >> 4;                  // 16 blocks per batch
    const int l0 = (blockIdx.x & 15) * TP_LB;

    const float4* vg = reinterpret_cast<const float4*>(v + ((size_t)b * LL + l0) * DD);
    #pragma unroll
    for (int i = 0; i < 16; ++i) {
        int j = t + 256 * i;                         // f4 index: l = j>>4, dq = (j&15)*4
        float4 f = vg[j];
        int l = j >> 4, dq = (j & 15) * 4;
        tile[dq + 0][l] = f2bf(f.x);
        tile[dq + 1][l] = f2bf(f.y);
        tile[dq + 2][l] = f2bf(f.z);
        tile[dq + 3][l] = f2bf(f.w);
    }
    __syncthreads();
    const int d = t >> 2, seg = t & 3;               // 64 ushorts per thread
    const uint4* src = reinterpret_cast<const uint4*>(&tile[d][seg * 64]);
    uint4* dst = reinterpret_cast<uint4*>(vt + ((size_t)b * DD + d) * LL + l0 + seg * 64);
    #pragma unroll
    for (int i = 0; i < 8; ++i) dst[i] = src[i];
}

// ============================================================================
// P1: masked mean via bf16 MFMA — EXACT R1 (best-measured) form.
// ============================================================================
__global__ __launch_bounds__(256) void k_mean(
    const int* __restrict__ mask,
    const unsigned short* __restrict__ vt,
    float* __restrict__ out)
{
    __shared__ float sums[4][4][16][16];             // [wave][dtile][row][col] 16 KB
    __shared__ float cnt_s[4][16];

    const int t     = threadIdx.x;
    const int wave  = t >> 6;
    const int lane  = t & 63;
    const int n0    = blockIdx.x * 16;
    const int b     = n0 / LQ;
    const int row_a = lane & 15;                     // MFMA m / B n index
    const int chunk = lane >> 4;                     // k-quad

    const int* mrow = mask + (size_t)(n0 + row_a) * LL + wave * 1024 + chunk * 8;
    const unsigned short* vbase = vt + (size_t)b * DD * LL + wave * 1024 + chunk * 8;

    f32x4 acc[4];
    #pragma unroll
    for (int dt = 0; dt < 4; ++dt) acc[dt] = (f32x4){0.f, 0.f, 0.f, 0.f};
    int cnt = 0;

    for (int l0 = 0; l0 < 1024; l0 += 32) {
        int4 ma = *reinterpret_cast<const int4*>(mrow + l0);
        int4 mb = *reinterpret_cast<const int4*>(mrow + l0 + 4);
        cnt += (ma.x != 0) + (ma.y != 0) + (ma.z != 0) + (ma.w != 0)
             + (mb.x != 0) + (mb.y != 0) + (mb.z != 0) + (mb.w != 0);
        unsigned int p[4];
        p[0] = (ma.x ? 0x3F80u : 0u) | (ma.y ? 0x3F800000u : 0u);
        p[1] = (ma.z ? 0x3F80u : 0u) | (ma.w ? 0x3F800000u : 0u);
        p[2] = (mb.x ? 0x3F80u : 0u) | (mb.y ? 0x3F800000u : 0u);
        p[3] = (mb.z ? 0x3F80u : 0u) | (mb.w ? 0x3F800000u : 0u);
        bf16x8 afrag = *reinterpret_cast<bf16x8*>(p);
        #pragma unroll
        for (int dt = 0; dt < 4; ++dt) {
            bf16x8 bfrag = *reinterpret_cast<const bf16x8*>(
                vbase + (size_t)(dt * 16 + row_a) * LL + l0);
            acc[dt] = __builtin_amdgcn_mfma_f32_16x16x32_bf16(afrag, bfrag, acc[dt], 0, 0, 0);
        }
    }
    cnt += __shfl_xor(cnt, 16);
    cnt += __shfl_xor(cnt, 32);                      // all lanes: count[row_a] (this l-range)
    if (lane < 16) cnt_s[wave][lane] = (float)cnt;
    #pragma unroll
    for (int dt = 0; dt < 4; ++dt)
        #pragma unroll
        for (int r = 0; r < 4; ++r)
            sums[wave][dt][chunk * 4 + r][row_a] = acc[dt][r];
    __syncthreads();

    // final: thread t -> d = t&63, rows rgrp*4..+3
    const int d = t & 63, rgrp = t >> 6;
    #pragma unroll
    for (int rr = 0; rr < 4; ++rr) {
        const int row = rgrp * 4 + rr;
        float s = sums[0][d >> 4][row][d & 15] + sums[1][d >> 4][row][d & 15]
                + sums[2][d >> 4][row][d & 15] + sums[3][d >> 4][row][d & 15];
        float c = cnt_s[0][row] + cnt_s[1][row] + cnt_s[2][row] + cnt_s[3][row];
        if (c < 1.f) c = 1.f;
        out[(size_t)(n0 + row) * DD + d] = s / c;
    }
}

// ============================================================================
// K1: masked scores -> ws, proven R1 body, now with rt0 offset so it can be
// launched as TWO half-row dispatches (~57us each). Purpose: any kernel
// >= ~63us must now surface in the profiler's top-5 (previously everything
// hid under k_scores' 114us instances).
// ============================================================================
__global__ __launch_bounds__(256)
__attribute__((amdgpu_waves_per_eu(2, 4)))
void k_scores(
    const float* __restrict__ q,
    const float* __restrict__ kmat,
    const int*   __restrict__ mask,
    float*       __restrict__ ws_sc,
    int rt0)
{
    __shared__ float4 Ss4[16 * LSP];                 // 32 KB: K^T [dc][l]

    const int t    = threadIdx.x;
    const int wave = t >> 6;
    const int lane = t & 63;
    const int rt   = (blockIdx.x >> 3) + rt0;        // 0..127 across both halves
    const int lc   = blockIdx.x & (NLC - 1);         // 0..7 -> XCD = blockIdx%8
    const int n0   = rt * RT;
    const int b    = n0 / LQ;
    const int lbase = lc * LC;

    int qbase[8];
    #pragma unroll
    for (int p = 0; p < 8; ++p)
        qbase[p] = __builtin_amdgcn_readfirstlane((n0 + wave * 8 + p) * DD);

    const float4* kg = reinterpret_cast<const float4*>(kmat) + (size_t)b * LL * 16;

    for (int s = 0; s < NPAIR; ++s) {
        const int l0 = lbase + s * LSP;
        __syncthreads();                             // Ss free
        #pragma unroll
        for (int i = 0; i < 2; ++i)
            #pragma unroll
            for (int j = 0; j < 4; ++j)
                Ss4[(wave * 4 + j) * LSP + lane + 64 * i] =
                    kg[(size_t)(l0 + lane + 64 * i) * 16 + wave * 4 + j];
        __syncthreads();

        float acc0[8], acc1[8];
        #pragma unroll
        for (int p = 0; p < 8; ++p) { acc0[p] = 0.f; acc1[p] = 0.f; }
        #pragma unroll
        for (int dc = 0; dc < 16; ++dc) {
            float4 ka = Ss4[dc * LSP + lane];
            float4 kb = Ss4[dc * LSP + 64 + lane];
            #pragma unroll
            for (int p = 0; p < 8; ++p) {
                float4 q4 = *reinterpret_cast<const float4*>(q + qbase[p] + dc * 4);
                acc0[p] += dot4(ka, q4);
                acc1[p] += dot4(kb, q4);
            }
        }
        #pragma unroll
        for (int p = 0; p < 8; ++p) {
            const int r = wave * 8 + p;
            int m0 = mask[(size_t)(n0 + r) * LL + l0 + lane];
            int m1 = mask[(size_t)(n0 + r) * LL + l0 + 64 + lane];
            ws_sc[(size_t)(n0 + r) * LL + l0 + lane]      = m0 ? acc0[p] * 0.125f : -FLT_MAX;
            ws_sc[(size_t)(n0 + r) * LL + l0 + 64 + lane] = m1 ? acc1[p] * 0.125f : -FLT_MAX;
        }
    }
}

// ============================================================================
// K2: per-wave exact radix top-32 — EXACT R1 (best-measured) form.
// ============================================================================
__global__ __launch_bounds__(256, 3) void k_select(
    const float* __restrict__ vmat,
    const float* __restrict__ ws,
    float*       __restrict__ out)
{
    __shared__ unsigned int hist[4][256];
    __shared__ unsigned int selKey[4][KEEP];
    __shared__ int          selIdx[4][KEEP];
    __shared__ float        wsel[4][KEEP];
    __shared__ int          selCnt[4], eqCnt[4];

    const int t    = threadIdx.x;
    const int wave = t >> 6;
    const int lane = t & 63;
    const int row  = blockIdx.x * 4 + wave;
    const int b    = row / LQ;

    float o = out[(size_t)row * DD + lane];          // mean from k_mean (early load)

    // ---- load row scores -> order-preserving uint keys (64 VGPRs) -----------
    unsigned int key[64];
    {
        const float4* sg = reinterpret_cast<const float4*>(ws) + (size_t)row * (LL / 4);
        #pragma unroll
        for (int i = 0; i < 16; ++i) {
            float4 f = sg[lane + 64 * i];
            float vals[4] = { f.x, f.y, f.z, f.w };
            #pragma unroll
            for (int c = 0; c < 4; ++c) {
                unsigned int u = __float_as_uint(vals[c]);
                key[4 * i + c] = ((int)u < 0) ? ~u : (u | 0x80000000u);
            }
        }
    }

    // ---- 4-pass radix select: exact 32nd-largest key + tie quota ------------
    unsigned int prefix = 0, quota = KEEP;
    #pragma unroll
    for (int pass = 0; pass < 4; ++pass) {
        const int shift = 24 - 8 * pass;
        const unsigned int hs = (pass == 0) ? 0u : (unsigned int)(32 - 8 * pass);
        reinterpret_cast<uint4*>(hist[wave])[lane] = make_uint4(0u, 0u, 0u, 0u);
        __asm__ volatile("s_waitcnt lgkmcnt(0)" ::: "memory");
        #pragma unroll
        for (int e = 0; e < 64; ++e) {
            bool act = (pass == 0) || ((key[e] >> hs) == prefix);
            if (act) atomicAdd(&hist[wave][(key[e] >> shift) & 255u], 1u);
        }
        __asm__ volatile("s_waitcnt lgkmcnt(0)" ::: "memory");
        uint4 h = reinterpret_cast<const uint4*>(hist[wave])[lane];
        unsigned int s4  = h.x + h.y + h.z + h.w;
        unsigned int suf = s4;
        #pragma unroll
        for (int off = 1; off < 64; off <<= 1) {
            unsigned int v = (unsigned int)__shfl_down((int)suf, off);
            if (lane + off < 64) suf += v;
        }
        unsigned int above = suf - s4;
        bool cond = (suf >= quota) && (above < quota);
        unsigned int Bq = 0, nq = 0;
        if (cond) {
            unsigned int hb[4] = { h.x, h.y, h.z, h.w };
            unsigned int run = above;
            int Bj = 0;
            #pragma unroll
            for (int j = 3; j >= 0; --j) {
                unsigned int nb = run + hb[j];
                if (nb >= quota) { Bj = j; break; }
                run = nb;
            }
            Bq = (unsigned int)(lane * 4 + Bj);
            nq = quota - run;
        }
        unsigned long long bal = __ballot(cond);
        int src = __ffsll(bal) - 1;
        Bq = (unsigned int)__shfl((int)Bq, src);
        nq = (unsigned int)__shfl((int)nq, src);
        prefix = (prefix << 8) | Bq;
        quota  = nq;
    }
    const unsigned int T = prefix;
    const bool take_eq = (T != MASKED_KEY);

    // ---- compact selected (val,idx) into LDS --------------------------------
    if (lane < KEEP) { wsel[wave][lane] = 0.f; selIdx[wave][lane] = 0; }
    if (lane == 0)   { selCnt[wave] = 0; eqCnt[wave] = 0; }
    __asm__ volatile("s_waitcnt lgkmcnt(0)" ::: "memory");
    #pragma unroll
    for (int e = 0; e < 64; ++e) {
        unsigned int k = key[e];
        if (k > T) {
            int slot = atomicAdd(&selCnt[wave], 1);
            selKey[wave][slot] = k;
            selIdx[wave][slot] = 256 * (e >> 2) + 4 * lane + (e & 3);
        } else if (take_eq && k == T) {
            int t2 = atomicAdd(&eqCnt[wave], 1);
            if (t2 < (int)quota) {
                int slot = atomicAdd(&selCnt[wave], 1);
                selKey[wave][slot] = k;
                selIdx[wave][slot] = 256 * (e >> 2) + 4 * lane + (e & 3);
            }
        }
    }
    __asm__ volatile("s_waitcnt lgkmcnt(0)" ::: "memory");
    const int S = selCnt[wave];

    // ---- softmax over selected + padded static gather -----------------------
    if (S > 0) {
        float vj = -FLT_MAX;
        if (lane < S) {
            unsigned int kk = selKey[wave][lane];
            unsigned int u = (kk & 0x80000000u) ? (kk ^ 0x80000000u) : ~kk;
            vj = __uint_as_float(u);
        }
        float mx = vj;
        #pragma unroll
        for (int off = 1; off < 64; off <<= 1) mx = fmaxf(mx, __shfl_xor(mx, off));
        float e = (lane < S) ? expf(vj - mx) : 0.f;
        float sum = e;
        #pragma unroll
        for (int off = 1; off < 64; off <<= 1) sum += __shfl_xor(sum, off);
        if (lane < S) wsel[wave][lane] = e / sum;
        __asm__ volatile("s_waitcnt lgkmcnt(0)" ::: "memory");
        const float* vb = vmat + (size_t)b * LL * DD + lane;
        #pragma unroll
        for (int j = 0; j < KEEP; ++j) {
            float wj = wsel[wave][j];
            int   ij = selIdx[wave][j];
            o += wj * vb[(size_t)ij * DD];
        }
    }
    out[(size_t)row * DD + lane] = o;
}

// ============================================================================
// Fallback (proven round-1 monolith) in case ws_size < WS_TOTAL*4.
// ============================================================================
#define QT   2
#define NT   256
#define NTILES (LL / NT)

__global__ __launch_bounds__(NT, 4) void ga_fused_fb(
    const float* __restrict__ q, const float* __restrict__ kmat,
    const float* __restrict__ vmat, const int* __restrict__ mask,
    float* __restrict__ out)
{
    __shared__ float sc[QT][LL];
    __shared__ float q_s[QT][DD];
    __shared__ unsigned long long mbits[QT][LL / 64];
    __shared__ float redv[4][QT][DD];
    __shared__ float mean_s[QT][DD];
    __shared__ int   count_s[QT];
    __shared__ int   sel_idx[QT][KEEP];
    __shared__ float sel_val[QT][KEEP];
    __shared__ int   sel_cnt[QT];
    __shared__ float wred[4];
    __shared__ int   ired[4];
    __shared__ int   brk;
    __shared__ float wgt[QT][KEEP];

    const int t = threadIdx.x, wave = t >> 6, lane = t & 63;
    const int n0 = blockIdx.x * QT, b = n0 / LQ;

    if (t < QT) sel_cnt[t] = 0;
    if (t < QT * DD) q_s[t >> 6][t & 63] = q[(size_t)(n0 + (t >> 6)) * DD + (t & 63)];
    __syncthreads();

    const float4* q4_0 = reinterpret_cast<const float4*>(&q_s[0][0]);
    const float4* q4_1 = reinterpret_cast<const float4*>(&q_s[1][0]);
    for (int tile = 0; tile < NTILES; ++tile) {
        int l = tile * NT + t;
        const float4* kr = reinterpret_cast<const float4*>(kmat + (size_t)(b * LL + l) * DD);
        float d0 = 0.f, d1 = 0.f;
        #pragma unroll
        for (int i = 0; i < 16; ++i) {
            float4 kk = kr[i], qa = q4_0[i], qb = q4_1[i];
            d0 += kk.x * qa.x + kk.y * qa.y + kk.z * qa.z + kk.w * qa.w;
            d1 += kk.x * qb.x + kk.y * qb.y + kk.z * qb.z + kk.w * qb.w;
        }
        int mv0 = mask[(size_t)n0 * LL + l];
        int mv1 = mask[(size_t)(n0 + 1) * LL + l];
        unsigned long long b0 = __ballot(mv0 != 0);
        unsigned long long b1 = __ballot(mv1 != 0);
        if (lane == 0) { mbits[0][tile * 4 + wave] = b0; mbits[1][tile * 4 + wave] = b1; }
        sc[0][l] = mv0 ? d0 * 0.125f : -FLT_MAX;
        sc[1][l] = mv1 ? d1 * 0.125f : -FLT_MAX;
    }
    __syncthreads();

    if (wave < QT) {
        int c = (int)__popcll(mbits[wave][lane]);
        for (int off = 32; off >= 1; off >>= 1) c += __shfl_down(c, off);
        if (lane == 0) count_s[wave] = c;
    }
    {
        float acc0 = 0.f, acc1 = 0.f;
        const int g = wave, d = lane;
        for (int wi = 0; wi < LL / 64; ++wi) {
            unsigned long long w0 = mbits[0][wi], w1 = mbits[1][wi];
            const float* vp = vmat + (size_t)(b * LL + wi * 64 + g) * DD + d;
            #pragma unroll 4
            for (int ii = 0; ii < 16; ++ii) {
                int sh = g + 4 * ii;
                float vv = vp[(size_t)(4 * ii) * DD];
                if ((w0 >> sh) & 1ULL) acc0 += vv;
                if ((w1 >> sh) & 1ULL) acc1 += vv;
            }
        }
        redv[g][0][d] = acc0; redv[g][1][d] = acc1;
    }
    __syncthreads();
    if (t < QT * DD) {
        int qt = t >> 6, dd = t & 63;
        float s2 = redv[0][qt][dd] + redv[1][qt][dd] + redv[2][qt][dd] + redv[3][qt][dd];
        int c = count_s[qt]; if (c < 1) c = 1;
        mean_s[qt][dd] = s2 / (float)c;
    }
    __syncthreads();

    for (int qt = 0; qt < QT; ++qt) {
        for (int s = 0; s < KEEP; ++s) {
            float m = -FLT_MAX; int mi = LL;
            for (int j = 0; j < NTILES; ++j) {
                int l = j * NT + t;
                float val = sc[qt][l];
                if (val > m) { m = val; mi = l; }
            }
            for (int off = 32; off >= 1; off >>= 1) {
                float ov = __shfl_down(m, off);
                int   oi = __shfl_down(mi, off);
                if (ov > m || (ov == m && oi < mi)) { m = ov; mi = oi; }
            }
            if (lane == 0) { wred[wave] = m; ired[wave] = mi; }
            __syncthreads();
            if (t == 0) {
                float bv = wred[0]; int bi = ired[0];
                for (int w2 = 1; w2 < 4; ++w2) {
                    float ov = wred[w2]; int oi = ired[w2];
                    if (ov > bv || (ov == bv && oi < bi)) { bv = ov; bi = oi; }
                }
                if (bv > -FLT_MAX) {
                    sel_idx[qt][s] = bi; sel_val[qt][s] = bv; sel_cnt[qt] = s + 1;
                    sc[qt][bi] = -FLT_MAX; brk = 0;
                } else brk = 1;
            }
            __syncthreads();
            if (brk) break;
        }
    }

    if (wave < QT) {
        int qt = wave, S = sel_cnt[qt];
        if (S > 0) {
            float mx = sel_val[qt][0];
            float e = 0.f;
            if (lane < S) e = expf(sel_val[qt][lane] - mx);
            float ssum = e;
            for (int off = 32; off >= 1; off >>= 1) ssum += __shfl_xor(ssum, off);
            if (lane < S) wgt[qt][lane] = e / ssum;
        }
    }
    __syncthreads();
    if (wave < QT) {
        int qt = wave, S = sel_cnt[qt];
        float o = mean_s[qt][lane];
        for (int j = 0; j < S; ++j)
            o += wgt[qt][j] * vmat[(size_t)(b * LL + sel_idx[qt][j]) * DD + lane];
        out[(size_t)(n0 + qt) * DD + lane] = o;
    }
}

// ============================================================================
extern "C" void kernel_launch(void* const* d_in, const int* in_sizes, int n_in,
                              void* d_out, int out_size, void* d_ws, size_t ws_size,
                              hipStream_t stream) {
    const float* q    = (const float*)d_in[0];
    const float* kmat = (const float*)d_in[1];
    const float* vmat = (const float*)d_in[2];
    const int*   mask = (const int*)d_in[3];
    float* out = (float*)d_out;

    const size_t need = (size_t)WS_TOTAL * sizeof(float);   // 71.30 MB (proven)
    if (ws_size >= need) {
        float* ws = (float*)d_ws;
        unsigned short* vt = (unsigned short*)(ws + WS_VT);
        // k_scores split into two half-row dispatches (diagnostic + same work)
        hipLaunchKernelGGL(k_scores, dim3((NROWS / RT / 2) * NLC), dim3(256), 0, stream,
                           q, kmat, mask, ws, 0);
        hipLaunchKernelGGL(k_scores, dim3((NROWS / RT / 2) * NLC), dim3(256), 0, stream,
                           q, kmat, mask, ws, NROWS / RT / 2);
        hipLaunchKernelGGL(k_vt, dim3(NB * 16), dim3(256), 0, stream, vmat, vt);
        hipLaunchKernelGGL(k_mean, dim3(NROWS / 16), dim3(256), 0, stream,
                           mask, vt, out);
        hipLaunchKernelGGL(k_select, dim3(NROWS / 4), dim3(256), 0, stream,
                           vmat, ws, out);
    } else {
        hipLaunchKernelGGL(ga_fused_fb, dim3(NROWS / QT), dim3(NT), 0, stream,
                           q, kmat, vmat, mask, out);
    }
}

// Round 8
// 293.730 us; speedup vs baseline: 1.4539x; 1.1039x over previous
//
#include <hip/hip_runtime.h>
#include <float.h>
#include <math.h>

// Problem constants (from reference setup_inputs)
#define LQ   512
#define LL   4096      // key length
#define DD   64        // d_qk == d_v
#define KEEP 32        // MAX_SET_SIZE
#define NB   8         // batches
#define NROWS (NB * LQ)    // 4096 flat query rows

// K1 tiling
#define RT    32           // query rows per block
#define NLC   8            // l-chunks per row
#define LC    (LL / NLC)   // 512
#define LSP   128          // l's per staging round
#define NPAIR (LC / LSP)   // 4

// ---- ws layout (floats) -----------------------------------------------------
// scores : [NROWS][LL] fp32                67.11 MB
// VT     : [NB][DD][LL] bf16                4.19 MB
// pcnt   : [4][NROWS] fp32 partial counts   0.07 MB
#define WS_VT    (NROWS * LL)                    // 16,777,216
#define WS_PC    (WS_VT + (NB * DD * LL) / 2)    // 17,825,792
#define WS_TOTAL (WS_PC + 4 * NROWS)             // 17,842,176 floats = 71.37 MB

#define MASKED_KEY 0x00800000u              // order-key of -FLT_MAX

typedef short  bf16x8 __attribute__((ext_vector_type(8)));
typedef float  f32x4  __attribute__((ext_vector_type(4)));

__device__ __forceinline__ float dot4(float4 a, float4 b) {
    return a.x * b.x + a.y * b.y + a.z * b.z + a.w * b.w;
}
__device__ __forceinline__ unsigned short f2bf(float f) {
    unsigned int u = __float_as_uint(f);
    return (unsigned short)((u + 0x7FFFu + ((u >> 16) & 1u)) >> 16);   // RNE
}

// ============================================================================
// P0: v[b][l][d] fp32 -> VT[b][d][l] bf16 (LDS tile transpose). UNCHANGED R1.
// ============================================================================
#define TP_LB 256
__global__ __launch_bounds__(256) void k_vt(
    const float* __restrict__ v, unsigned short* __restrict__ vt)
{
    __shared__ unsigned short tile[DD][TP_LB + 8];   // +8 ushorts: bank de-phase
    const int t  = threadIdx.x;
    const int b  = blockIdx.x >> 4;                  // 16 blocks per batch
    const int l0 = (blockIdx.x & 15) * TP_LB;

    const float4* vg = reinterpret_cast<const float4*>(v + ((size_t)b * LL + l0) * DD);
    #pragma unroll
    for (int i = 0; i < 16; ++i) {
        int j = t + 256 * i;                         // f4 index: l = j>>4, dq = (j&15)*4
        float4 f = vg[j];
        int l = j >> 4, dq = (j & 15) * 4;
        tile[dq + 0][l] = f2bf(f.x);
        tile[dq + 1][l] = f2bf(f.y);
        tile[dq + 2][l] = f2bf(f.z);
        tile[dq + 3][l] = f2bf(f.w);
    }
    __syncthreads();
    const int d = t >> 2, seg = t & 3;               // 64 ushorts per thread
    const uint4* src = reinterpret_cast<const uint4*>(&tile[d][seg * 64]);
    uint4* dst = reinterpret_cast<uint4*>(vt + ((size_t)b * DD + d) * LL + l0 + seg * 64);
    #pragma unroll
    for (int i = 0; i < 8; ++i) dst[i] = src[i];
}

// ============================================================================
// P1 v3: masked partial-mean via bf16 MFMA. Inner loop BYTE-IDENTICAL to the
// proven R1 form; only the geometry changes: grid = 256 row-groups x 4
// l-quarters (1024 blocks -> 4 blocks/CU, 4 waves/SIMD vs R1's 1). Each
// block covers 16 rows x 1024 l (wave owns 256 l), reduces its 4 waves in
// LDS as before, then atomicAdd's the partial sum into the ZEROED out buffer
// and writes its quarter-count to pcnt[lcq][row] (no atomics). k_select
// finalizes mean = sum / clip(count,1). Mechanism: R1 k_mean ran at 1
// wave/SIMD -> latency-bound on scattered 16-B mask granules (~70us vs
// ~11us floor); 4x TLP hides it.
// ============================================================================
__global__ __launch_bounds__(256) void k_mean(
    const int* __restrict__ mask,
    const unsigned short* __restrict__ vt,
    float* __restrict__ out,
    float* __restrict__ pcnt)
{
    __shared__ float sums[4][4][16][16];             // [wave][dtile][row][col] 16 KB
    __shared__ float cnt_s[4][16];

    const int t     = threadIdx.x;
    const int wave  = t >> 6;
    const int lane  = t & 63;
    const int lcq   = blockIdx.x & 3;                // l-quarter
    const int rg    = blockIdx.x >> 2;               // row-group
    const int n0    = rg * 16;
    const int b     = n0 / LQ;
    const int row_a = lane & 15;                     // MFMA m / B n index
    const int chunk = lane >> 4;                     // k-quad
    const int lb    = lcq * 1024 + wave * 256;       // wave's l-base

    const int* mrow = mask + (size_t)(n0 + row_a) * LL + lb + chunk * 8;
    const unsigned short* vbase = vt + (size_t)b * DD * LL + lb + chunk * 8;

    f32x4 acc[4];
    #pragma unroll
    for (int dt = 0; dt < 4; ++dt) acc[dt] = (f32x4){0.f, 0.f, 0.f, 0.f};
    int cnt = 0;

    for (int l0 = 0; l0 < 256; l0 += 32) {
        int4 ma = *reinterpret_cast<const int4*>(mrow + l0);
        int4 mb = *reinterpret_cast<const int4*>(mrow + l0 + 4);
        cnt += (ma.x != 0) + (ma.y != 0) + (ma.z != 0) + (ma.w != 0)
             + (mb.x != 0) + (mb.y != 0) + (mb.z != 0) + (mb.w != 0);
        unsigned int p[4];
        p[0] = (ma.x ? 0x3F80u : 0u) | (ma.y ? 0x3F800000u : 0u);
        p[1] = (ma.z ? 0x3F80u : 0u) | (ma.w ? 0x3F800000u : 0u);
        p[2] = (mb.x ? 0x3F80u : 0u) | (mb.y ? 0x3F800000u : 0u);
        p[3] = (mb.z ? 0x3F80u : 0u) | (mb.w ? 0x3F800000u : 0u);
        bf16x8 afrag = *reinterpret_cast<bf16x8*>(p);
        #pragma unroll
        for (int dt = 0; dt < 4; ++dt) {
            bf16x8 bfrag = *reinterpret_cast<const bf16x8*>(
                vbase + (size_t)(dt * 16 + row_a) * LL + l0);
            acc[dt] = __builtin_amdgcn_mfma_f32_16x16x32_bf16(afrag, bfrag, acc[dt], 0, 0, 0);
        }
    }
    cnt += __shfl_xor(cnt, 16);
    cnt += __shfl_xor(cnt, 32);                      // all lanes: count[row_a] (this l-range)
    if (lane < 16) cnt_s[wave][lane] = (float)cnt;
    #pragma unroll
    for (int dt = 0; dt < 4; ++dt)
        #pragma unroll
        for (int r = 0; r < 4; ++r)
            sums[wave][dt][chunk * 4 + r][row_a] = acc[dt][r];
    __syncthreads();

    // final: thread t -> d = t&63, rows rgrp*4..+3; ATOMIC partial accumulate
    const int d = t & 63, rgrp = t >> 6;
    #pragma unroll
    for (int rr = 0; rr < 4; ++rr) {
        const int row = rgrp * 4 + rr;
        float s = sums[0][d >> 4][row][d & 15] + sums[1][d >> 4][row][d & 15]
                + sums[2][d >> 4][row][d & 15] + sums[3][d >> 4][row][d & 15];
        float c = cnt_s[0][row] + cnt_s[1][row] + cnt_s[2][row] + cnt_s[3][row];
        atomicAdd(&out[(size_t)(n0 + row) * DD + d], s);
        if (d == 0) pcnt[lcq * NROWS + n0 + row] = c;
    }
}

// ============================================================================
// K1: masked scores -> ws. EXACT proven R1 form, single dispatch (114us).
// ============================================================================
__global__ __launch_bounds__(256)
__attribute__((amdgpu_waves_per_eu(2, 4)))
void k_scores(
    const float* __restrict__ q,
    const float* __restrict__ kmat,
    const int*   __restrict__ mask,
    float*       __restrict__ ws_sc)
{
    __shared__ float4 Ss4[16 * LSP];                 // 32 KB: K^T [dc][l]

    const int t    = threadIdx.x;
    const int wave = t >> 6;
    const int lane = t & 63;
    const int rt   = blockIdx.x >> 3;                // 0..127
    const int lc   = blockIdx.x & (NLC - 1);         // 0..7 -> XCD = blockIdx%8
    const int n0   = rt * RT;
    const int b    = n0 / LQ;
    const int lbase = lc * LC;

    int qbase[8];
    #pragma unroll
    for (int p = 0; p < 8; ++p)
        qbase[p] = __builtin_amdgcn_readfirstlane((n0 + wave * 8 + p) * DD);

    const float4* kg = reinterpret_cast<const float4*>(kmat) + (size_t)b * LL * 16;

    for (int s = 0; s < NPAIR; ++s) {
        const int l0 = lbase + s * LSP;
        __syncthreads();                             // Ss free
        #pragma unroll
        for (int i = 0; i < 2; ++i)
            #pragma unroll
            for (int j = 0; j < 4; ++j)
                Ss4[(wave * 4 + j) * LSP + lane + 64 * i] =
                    kg[(size_t)(l0 + lane + 64 * i) * 16 + wave * 4 + j];
        __syncthreads();

        float acc0[8], acc1[8];
        #pragma unroll
        for (int p = 0; p < 8; ++p) { acc0[p] = 0.f; acc1[p] = 0.f; }
        #pragma unroll
        for (int dc = 0; dc < 16; ++dc) {
            float4 ka = Ss4[dc * LSP + lane];
            float4 kb = Ss4[dc * LSP + 64 + lane];
            #pragma unroll
            for (int p = 0; p < 8; ++p) {
                float4 q4 = *reinterpret_cast<const float4*>(q + qbase[p] + dc * 4);
                acc0[p] += dot4(ka, q4);
                acc1[p] += dot4(kb, q4);
            }
        }
        #pragma unroll
        for (int p = 0; p < 8; ++p) {
            const int r = wave * 8 + p;
            int m0 = mask[(size_t)(n0 + r) * LL + l0 + lane];
            int m1 = mask[(size_t)(n0 + r) * LL + l0 + 64 + lane];
            ws_sc[(size_t)(n0 + r) * LL + l0 + lane]      = m0 ? acc0[p] * 0.125f : -FLT_MAX;
            ws_sc[(size_t)(n0 + r) * LL + l0 + 64 + lane] = m1 ? acc1[p] * 0.125f : -FLT_MAX;
        }
    }
}

// ============================================================================
// K2: per-wave exact radix top-32 — proven R1 form + mean finalize
// (sum from zeroed+atomic out, counts from pcnt, divide by clip).
// ============================================================================
__global__ __launch_bounds__(256, 3) void k_select(
    const float* __restrict__ vmat,
    const float* __restrict__ ws,
    const float* __restrict__ pcnt,
    float*       __restrict__ out)
{
    __shared__ unsigned int hist[4][256];
    __shared__ unsigned int selKey[4][KEEP];
    __shared__ int          selIdx[4][KEEP];
    __shared__ float        wsel[4][KEEP];
    __shared__ int          selCnt[4], eqCnt[4];

    const int t    = threadIdx.x;
    const int wave = t >> 6;
    const int lane = t & 63;
    const int row  = blockIdx.x * 4 + wave;
    const int b    = row / LQ;

    // ---- mean finalize: sum (atomic-accumulated) / clip(count,1) ------------
    float o = out[(size_t)row * DD + lane];
    {
        float cc = pcnt[row] + pcnt[NROWS + row]
                 + pcnt[2 * NROWS + row] + pcnt[3 * NROWS + row];
        if (cc < 1.f) cc = 1.f;
        o /= cc;
    }

    // ---- load row scores -> order-preserving uint keys (64 VGPRs) -----------
    unsigned int key[64];
    {
        const float4* sg = reinterpret_cast<const float4*>(ws) + (size_t)row * (LL / 4);
        #pragma unroll
        for (int i = 0; i < 16; ++i) {
            float4 f = sg[lane + 64 * i];
            float vals[4] = { f.x, f.y, f.z, f.w };
            #pragma unroll
            for (int c = 0; c < 4; ++c) {
                unsigned int u = __float_as_uint(vals[c]);
                key[4 * i + c] = ((int)u < 0) ? ~u : (u | 0x80000000u);
            }
        }
    }

    // ---- 4-pass radix select: exact 32nd-largest key + tie quota ------------
    unsigned int prefix = 0, quota = KEEP;
    #pragma unroll
    for (int pass = 0; pass < 4; ++pass) {
        const int shift = 24 - 8 * pass;
        const unsigned int hs = (pass == 0) ? 0u : (unsigned int)(32 - 8 * pass);
        reinterpret_cast<uint4*>(hist[wave])[lane] = make_uint4(0u, 0u, 0u, 0u);
        __asm__ volatile("s_waitcnt lgkmcnt(0)" ::: "memory");
        #pragma unroll
        for (int e = 0; e < 64; ++e) {
            bool act = (pass == 0) || ((key[e] >> hs) == prefix);
            if (act) atomicAdd(&hist[wave][(key[e] >> shift) & 255u], 1u);
        }
        __asm__ volatile("s_waitcnt lgkmcnt(0)" ::: "memory");
        uint4 h = reinterpret_cast<const uint4*>(hist[wave])[lane];
        unsigned int s4  = h.x + h.y + h.z + h.w;
        unsigned int suf = s4;
        #pragma unroll
        for (int off = 1; off < 64; off <<= 1) {
            unsigned int v = (unsigned int)__shfl_down((int)suf, off);
            if (lane + off < 64) suf += v;
        }
        unsigned int above = suf - s4;
        bool cond = (suf >= quota) && (above < quota);
        unsigned int Bq = 0, nq = 0;
        if (cond) {
            unsigned int hb[4] = { h.x, h.y, h.z, h.w };
            unsigned int run = above;
            int Bj = 0;
            #pragma unroll
            for (int j = 3; j >= 0; --j) {
                unsigned int nb = run + hb[j];
                if (nb >= quota) { Bj = j; break; }
                run = nb;
            }
            Bq = (unsigned int)(lane * 4 + Bj);
            nq = quota - run;
        }
        unsigned long long bal = __ballot(cond);
        int src = __ffsll(bal) - 1;
        Bq = (unsigned int)__shfl((int)Bq, src);
        nq = (unsigned int)__shfl((int)nq, src);
        prefix = (prefix << 8) | Bq;
        quota  = nq;
    }
    const unsigned int T = prefix;
    const bool take_eq = (T != MASKED_KEY);

    // ---- compact selected (val,idx) into LDS --------------------------------
    if (lane < KEEP) { wsel[wave][lane] = 0.f; selIdx[wave][lane] = 0; }
    if (lane == 0)   { selCnt[wave] = 0; eqCnt[wave] = 0; }
    __asm__ volatile("s_waitcnt lgkmcnt(0)" ::: "memory");
    #pragma unroll
    for (int e = 0; e < 64; ++e) {
        unsigned int k = key[e];
        if (k > T) {
            int slot = atomicAdd(&selCnt[wave], 1);
            selKey[wave][slot] = k;
            selIdx[wave][slot] = 256 * (e >> 2) + 4 * lane + (e & 3);
        } else if (take_eq && k == T) {
            int t2 = atomicAdd(&eqCnt[wave], 1);
            if (t2 < (int)quota) {
                int slot = atomicAdd(&selCnt[wave], 1);
                selKey[wave][slot] = k;
                selIdx[wave][slot] = 256 * (e >> 2) + 4 * lane + (e & 3);
            }
        }
    }
    __asm__ volatile("s_waitcnt lgkmcnt(0)" ::: "memory");
    const int S = selCnt[wave];

    // ---- softmax over selected + padded static gather -----------------------
    if (S > 0) {
        float vj = -FLT_MAX;
        if (lane < S) {
            unsigned int kk = selKey[wave][lane];
            unsigned int u = (kk & 0x80000000u) ? (kk ^ 0x80000000u) : ~kk;
            vj = __uint_as_float(u);
        }
        float mx = vj;
        #pragma unroll
        for (int off = 1; off < 64; off <<= 1) mx = fmaxf(mx, __shfl_xor(mx, off));
        float e = (lane < S) ? expf(vj - mx) : 0.f;
        float sum = e;
        #pragma unroll
        for (int off = 1; off < 64; off <<= 1) sum += __shfl_xor(sum, off);
        if (lane < S) wsel[wave][lane] = e / sum;
        __asm__ volatile("s_waitcnt lgkmcnt(0)" ::: "memory");
        const float* vb = vmat + (size_t)b * LL * DD + lane;
        #pragma unroll
        for (int j = 0; j < KEEP; ++j) {
            float wj = wsel[wave][j];
            int   ij = selIdx[wave][j];
            o += wj * vb[(size_t)ij * DD];
        }
    }
    out[(size_t)row * DD + lane] = o;
}

// ============================================================================
// Fallback (proven round-1 monolith) in case ws_size < WS_TOTAL*4.
// ============================================================================
#define QT   2
#define NT   256
#define NTILES (LL / NT)

__global__ __launch_bounds__(NT, 4) void ga_fused_fb(
    const float* __restrict__ q, const float* __restrict__ kmat,
    const float* __restrict__ vmat, const int* __restrict__ mask,
    float* __restrict__ out)
{
    __shared__ float sc[QT][LL];
    __shared__ float q_s[QT][DD];
    __shared__ unsigned long long mbits[QT][LL / 64];
    __shared__ float redv[4][QT][DD];
    __shared__ float mean_s[QT][DD];
    __shared__ int   count_s[QT];
    __shared__ int   sel_idx[QT][KEEP];
    __shared__ float sel_val[QT][KEEP];
    __shared__ int   sel_cnt[QT];
    __shared__ float wred[4];
    __shared__ int   ired[4];
    __shared__ int   brk;
    __shared__ float wgt[QT][KEEP];

    const int t = threadIdx.x, wave = t >> 6, lane = t & 63;
    const int n0 = blockIdx.x * QT, b = n0 / LQ;

    if (t < QT) sel_cnt[t] = 0;
    if (t < QT * DD) q_s[t >> 6][t & 63] = q[(size_t)(n0 + (t >> 6)) * DD + (t & 63)];
    __syncthreads();

    const float4* q4_0 = reinterpret_cast<const float4*>(&q_s[0][0]);
    const float4* q4_1 = reinterpret_cast<const float4*>(&q_s[1][0]);
    for (int tile = 0; tile < NTILES; ++tile) {
        int l = tile * NT + t;
        const float4* kr = reinterpret_cast<const float4*>(kmat + (size_t)(b * LL + l) * DD);
        float d0 = 0.f, d1 = 0.f;
        #pragma unroll
        for (int i = 0; i < 16; ++i) {
            float4 kk = kr[i], qa = q4_0[i], qb = q4_1[i];
            d0 += kk.x * qa.x + kk.y * qa.y + kk.z * qa.z + kk.w * qa.w;
            d1 += kk.x * qb.x + kk.y * qb.y + kk.z * qb.z + kk.w * qb.w;
        }
        int mv0 = mask[(size_t)n0 * LL + l];
        int mv1 = mask[(size_t)(n0 + 1) * LL + l];
        unsigned long long b0 = __ballot(mv0 != 0);
        unsigned long long b1 = __ballot(mv1 != 0);
        if (lane == 0) { mbits[0][tile * 4 + wave] = b0; mbits[1][tile * 4 + wave] = b1; }
        sc[0][l] = mv0 ? d0 * 0.125f : -FLT_MAX;
        sc[1][l] = mv1 ? d1 * 0.125f : -FLT_MAX;
    }
    __syncthreads();

    if (wave < QT) {
        int c = (int)__popcll(mbits[wave][lane]);
        for (int off = 32; off >= 1; off >>= 1) c += __shfl_down(c, off);
        if (lane == 0) count_s[wave] = c;
    }
    {
        float acc0 = 0.f, acc1 = 0.f;
        const int g = wave, d = lane;
        for (int wi = 0; wi < LL / 64; ++wi) {
            unsigned long long w0 = mbits[0][wi], w1 = mbits[1][wi];
            const float* vp = vmat + (size_t)(b * LL + wi * 64 + g) * DD + d;
            #pragma unroll 4
            for (int ii = 0; ii < 16; ++ii) {
                int sh = g + 4 * ii;
                float vv = vp[(size_t)(4 * ii) * DD];
                if ((w0 >> sh) & 1ULL) acc0 += vv;
                if ((w1 >> sh) & 1ULL) acc1 += vv;
            }
        }
        redv[g][0][d] = acc0; redv[g][1][d] = acc1;
    }
    __syncthreads();
    if (t < QT * DD) {
        int qt = t >> 6, dd = t & 63;
        float s2 = redv[0][qt][dd] + redv[1][qt][dd] + redv[2][qt][dd] + redv[3][qt][dd];
        int c = count_s[qt]; if (c < 1) c = 1;
        mean_s[qt][dd] = s2 / (float)c;
    }
    __syncthreads();

    for (int qt = 0; qt < QT; ++qt) {
        for (int s = 0; s < KEEP; ++s) {
            float m = -FLT_MAX; int mi = LL;
            for (int j = 0; j < NTILES; ++j) {
                int l = j * NT + t;
                float val = sc[qt][l];
                if (val > m) { m = val; mi = l; }
            }
            for (int off = 32; off >= 1; off >>= 1) {
                float ov = __shfl_down(m, off);
                int   oi = __shfl_down(mi, off);
                if (ov > m || (ov == m && oi < mi)) { m = ov; mi = oi; }
            }
            if (lane == 0) { wred[wave] = m; ired[wave] = mi; }
            __syncthreads();
            if (t == 0) {
                float bv = wred[0]; int bi = ired[0];
                for (int w2 = 1; w2 < 4; ++w2) {
                    float ov = wred[w2]; int oi = ired[w2];
                    if (ov > bv || (ov == bv && oi < bi)) { bv = ov; bi = oi; }
                }
                if (bv > -FLT_MAX) {
                    sel_idx[qt][s] = bi; sel_val[qt][s] = bv; sel_cnt[qt] = s + 1;
                    sc[qt][bi] = -FLT_MAX; brk = 0;
                } else brk = 1;
            }
            __syncthreads();
            if (brk) break;
        }
    }

    if (wave < QT) {
        int qt = wave, S = sel_cnt[qt];
        if (S > 0) {
            float mx = sel_val[qt][0];
            float e = 0.f;
            if (lane < S) e = expf(sel_val[qt][lane] - mx);
            float ssum = e;
            for (int off = 32; off >= 1; off >>= 1) ssum += __shfl_xor(ssum, off);
            if (lane < S) wgt[qt][lane] = e / ssum;
        }
    }
    __syncthreads();
    if (wave < QT) {
        int qt = wave, S = sel_cnt[qt];
        float o = mean_s[qt][lane];
        for (int j = 0; j < S; ++j)
            o += wgt[qt][j] * vmat[(size_t)(b * LL + sel_idx[qt][j]) * DD + lane];
        out[(size_t)(n0 + qt) * DD + lane] = o;
    }
}

// ============================================================================
extern "C" void kernel_launch(void* const* d_in, const int* in_sizes, int n_in,
                              void* d_out, int out_size, void* d_ws, size_t ws_size,
                              hipStream_t stream) {
    const float* q    = (const float*)d_in[0];
    const float* kmat = (const float*)d_in[1];
    const float* vmat = (const float*)d_in[2];
    const int*   mask = (const int*)d_in[3];
    float* out = (float*)d_out;

    const size_t need = (size_t)WS_TOTAL * sizeof(float);   // 71.37 MB (== proven)
    if (ws_size >= need) {
        float* ws = (float*)d_ws;
        unsigned short* vt = (unsigned short*)(ws + WS_VT);
        float* pcnt = ws + WS_PC;
        hipMemsetAsync(out, 0, (size_t)NROWS * DD * sizeof(float), stream);
        hipLaunchKernelGGL(k_scores, dim3((NROWS / RT) * NLC), dim3(256), 0, stream,
                           q, kmat, mask, ws);
        hipLaunchKernelGGL(k_vt, dim3(NB * 16), dim3(256), 0, stream, vmat, vt);
        hipLaunchKernelGGL(k_mean, dim3((NROWS / 16) * 4), dim3(256), 0, stream,
                           mask, vt, out, pcnt);
        hipLaunchKernelGGL(k_select, dim3(NROWS / 4), dim3(256), 0, stream,
                           vmat, ws, pcnt, out);
    } else {
        hipLaunchKernelGGL(ga_fused_fb, dim3(NROWS / QT), dim3(NT), 0, stream,
                           q, kmat, vmat, mask, out);
    }
}

// Round 9
// 253.747 us; speedup vs baseline: 1.6830x; 1.1576x over previous
//
#include <hip/hip_runtime.h>
#include <float.h>
#include <math.h>

// Problem constants (from reference setup_inputs)
#define LQ   512
#define LL   4096      // key length
#define DD   64        // d_qk == d_v
#define KEEP 32        // MAX_SET_SIZE
#define NB   8         // batches
#define NROWS (NB * LQ)    // 4096 flat query rows

// ---- ws layout (floats) -----------------------------------------------------
// scores : [NROWS][LL] fp32                67.11 MB
// VT     : [NB][DD][LL] bf16                4.19 MB
// pcnt   : [4][NROWS] fp32 partial counts   0.07 MB
#define WS_VT    (NROWS * LL)                    // 16,777,216
#define WS_PC    (WS_VT + (NB * DD * LL) / 2)    // 17,825,792
#define WS_TOTAL (WS_PC + 4 * NROWS)             // 17,842,176 floats = 71.37 MB

#define MASKED_KEY 0x00800000u              // order-key of -FLT_MAX

typedef short  bf16x8 __attribute__((ext_vector_type(8)));
typedef float  f32x4  __attribute__((ext_vector_type(4)));

__device__ __forceinline__ float dot4(float4 a, float4 b) {
    return a.x * b.x + a.y * b.y + a.z * b.z + a.w * b.w;
}
__device__ __forceinline__ unsigned short f2bf(float f) {
    unsigned int u = __float_as_uint(f);
    return (unsigned short)((u + 0x7FFFu + ((u >> 16) & 1u)) >> 16);   // RNE
}

// ============================================================================
// P0: v[b][l][d] fp32 -> VT[b][d][l] bf16 (LDS tile transpose). UNCHANGED R1.
// ============================================================================
#define TP_LB 256
__global__ __launch_bounds__(256) void k_vt(
    const float* __restrict__ v, unsigned short* __restrict__ vt)
{
    __shared__ unsigned short tile[DD][TP_LB + 8];   // +8 ushorts: bank de-phase
    const int t  = threadIdx.x;
    const int b  = blockIdx.x >> 4;                  // 16 blocks per batch
    const int l0 = (blockIdx.x & 15) * TP_LB;

    const float4* vg = reinterpret_cast<const float4*>(v + ((size_t)b * LL + l0) * DD);
    #pragma unroll
    for (int i = 0; i < 16; ++i) {
        int j = t + 256 * i;                         // f4 index: l = j>>4, dq = (j&15)*4
        float4 f = vg[j];
        int l = j >> 4, dq = (j & 15) * 4;
        tile[dq + 0][l] = f2bf(f.x);
        tile[dq + 1][l] = f2bf(f.y);
        tile[dq + 2][l] = f2bf(f.z);
        tile[dq + 3][l] = f2bf(f.w);
    }
    __syncthreads();
    const int d = t >> 2, seg = t & 3;               // 64 ushorts per thread
    const uint4* src = reinterpret_cast<const uint4*>(&tile[d][seg * 64]);
    uint4* dst = reinterpret_cast<uint4*>(vt + ((size_t)b * DD + d) * LL + l0 + seg * 64);
    #pragma unroll
    for (int i = 0; i < 8; ++i) dst[i] = src[i];
}

// ============================================================================
// P1 v3: masked partial-mean via bf16 MFMA (R8 form, 4 l-quarters, atomics).
// UNCHANGED (control).
// ============================================================================
__global__ __launch_bounds__(256) void k_mean(
    const int* __restrict__ mask,
    const unsigned short* __restrict__ vt,
    float* __restrict__ out,
    float* __restrict__ pcnt)
{
    __shared__ float sums[4][4][16][16];             // [wave][dtile][row][col] 16 KB
    __shared__ float cnt_s[4][16];

    const int t     = threadIdx.x;
    const int wave  = t >> 6;
    const int lane  = t & 63;
    const int lcq   = blockIdx.x & 3;                // l-quarter
    const int rg    = blockIdx.x >> 2;               // row-group
    const int n0    = rg * 16;
    const int b     = n0 / LQ;
    const int row_a = lane & 15;                     // MFMA m / B n index
    const int chunk = lane >> 4;                     // k-quad
    const int lb    = lcq * 1024 + wave * 256;       // wave's l-base

    const int* mrow = mask + (size_t)(n0 + row_a) * LL + lb + chunk * 8;
    const unsigned short* vbase = vt + (size_t)b * DD * LL + lb + chunk * 8;

    f32x4 acc[4];
    #pragma unroll
    for (int dt = 0; dt < 4; ++dt) acc[dt] = (f32x4){0.f, 0.f, 0.f, 0.f};
    int cnt = 0;

    for (int l0 = 0; l0 < 256; l0 += 32) {
        int4 ma = *reinterpret_cast<const int4*>(mrow + l0);
        int4 mb = *reinterpret_cast<const int4*>(mrow + l0 + 4);
        cnt += (ma.x != 0) + (ma.y != 0) + (ma.z != 0) + (ma.w != 0)
             + (mb.x != 0) + (mb.y != 0) + (mb.z != 0) + (mb.w != 0);
        unsigned int p[4];
        p[0] = (ma.x ? 0x3F80u : 0u) | (ma.y ? 0x3F800000u : 0u);
        p[1] = (ma.z ? 0x3F80u : 0u) | (ma.w ? 0x3F800000u : 0u);
        p[2] = (mb.x ? 0x3F80u : 0u) | (mb.y ? 0x3F800000u : 0u);
        p[3] = (mb.z ? 0x3F80u : 0u) | (mb.w ? 0x3F800000u : 0u);
        bf16x8 afrag = *reinterpret_cast<bf16x8*>(p);
        #pragma unroll
        for (int dt = 0; dt < 4; ++dt) {
            bf16x8 bfrag = *reinterpret_cast<const bf16x8*>(
                vbase + (size_t)(dt * 16 + row_a) * LL + l0);
            acc[dt] = __builtin_amdgcn_mfma_f32_16x16x32_bf16(afrag, bfrag, acc[dt], 0, 0, 0);
        }
    }
    cnt += __shfl_xor(cnt, 16);
    cnt += __shfl_xor(cnt, 32);                      // all lanes: count[row_a] (this l-range)
    if (lane < 16) cnt_s[wave][lane] = (float)cnt;
    #pragma unroll
    for (int dt = 0; dt < 4; ++dt)
        #pragma unroll
        for (int r = 0; r < 4; ++r)
            sums[wave][dt][chunk * 4 + r][row_a] = acc[dt][r];
    __syncthreads();

    // final: thread t -> d = t&63, rows rgrp*4..+3; ATOMIC partial accumulate
    const int d = t & 63, rgrp = t >> 6;
    #pragma unroll
    for (int rr = 0; rr < 4; ++rr) {
        const int row = rgrp * 4 + rr;
        float s = sums[0][d >> 4][row][d & 15] + sums[1][d >> 4][row][d & 15]
                + sums[2][d >> 4][row][d & 15] + sums[3][d >> 4][row][d & 15];
        float c = cnt_s[0][row] + cnt_s[1][row] + cnt_s[2][row] + cnt_s[3][row];
        atomicAdd(&out[(size_t)(n0 + row) * DD + d], s);
        if (d == 0) pcnt[lcq * NROWS + n0 + row] = c;
    }
}

// ============================================================================
// K1 v2: register-K scores. Lane = one l-column; K row (64 f) lives in 16
// float4 VGPRs loaded once; q is wave-uniform (readfirstlane base + const
// offsets -> scalar loads on the SMEM pipe); mask prefetched as 16 coalesced
// dwords; per row p: 64 FMA with 4 independent chains; coalesced dword store.
// Replaces the LDS-staged form whose barriers + ds_reads + per-(dc,p) loads
// held it at 112us (5-8x above its 14us FMA / 18us BW floors).
// Summation order (d-sequential, x->w) identical to old kernel -> scores
// bit-identical. Wave = 16 rows x 64 l; grid = 256 rowgroups x 16 l-chunks.
// ============================================================================
__global__ __launch_bounds__(256) void k_scores(
    const float* __restrict__ q,
    const float* __restrict__ kmat,
    const int*   __restrict__ mask,
    float*       __restrict__ ws_sc)
{
    const int t    = threadIdx.x;
    const int wave = t >> 6;
    const int lane = t & 63;
    const int lc   = blockIdx.x & 15;                // l-chunk -> XCD spread (%8)
    const int rg   = blockIdx.x >> 4;                // row-group 0..255
    const int n0   = rg * 16;
    const int b    = n0 / LQ;
    const int l    = lc * 256 + wave * 64 + lane;    // this lane's l

    // ---- K row -> 64 VGPR (16 float4), loaded once --------------------------
    const float4* kr = reinterpret_cast<const float4*>(kmat + ((size_t)b * LL + l) * DD);
    float4 kreg[16];
    #pragma unroll
    for (int i = 0; i < 16; ++i) kreg[i] = kr[i];

    // ---- mask prefetch: 16 rows, coalesced dword each -----------------------
    int mreg[16];
    #pragma unroll
    for (int p = 0; p < 16; ++p)
        mreg[p] = mask[(size_t)(n0 + p) * LL + l];

    const int qb = __builtin_amdgcn_readfirstlane(n0 * DD);
    #pragma unroll
    for (int p = 0; p < 16; ++p) {
        const float4* qp = reinterpret_cast<const float4*>(q + qb + p * DD);
        // 4 independent accumulation chains (break serial fma dependency)
        float ax = 0.f, ay = 0.f, az = 0.f, aw = 0.f;
        #pragma unroll
        for (int i = 0; i < 16; ++i) {
            float4 qv = qp[i];                       // wave-uniform -> s_load
            ax = fmaf(qv.x, kreg[i].x, ax);
            ay = fmaf(qv.y, kreg[i].y, ay);
            az = fmaf(qv.z, kreg[i].z, az);
            aw = fmaf(qv.w, kreg[i].w, aw);
        }
        float acc = ax + ay + az + aw;
        ws_sc[(size_t)(n0 + p) * LL + l] = mreg[p] ? acc * 0.125f : -FLT_MAX;
    }
}

// ============================================================================
// K2: per-wave exact radix top-32 — R8 form (mean finalize + radix + gather).
// UNCHANGED (control).
// ============================================================================
__global__ __launch_bounds__(256, 3) void k_select(
    const float* __restrict__ vmat,
    const float* __restrict__ ws,
    const float* __restrict__ pcnt,
    float*       __restrict__ out)
{
    __shared__ unsigned int hist[4][256];
    __shared__ unsigned int selKey[4][KEEP];
    __shared__ int          selIdx[4][KEEP];
    __shared__ float        wsel[4][KEEP];
    __shared__ int          selCnt[4], eqCnt[4];

    const int t    = threadIdx.x;
    const int wave = t >> 6;
    const int lane = t & 63;
    const int row  = blockIdx.x * 4 + wave;
    const int b    = row / LQ;

    // ---- mean finalize: sum (atomic-accumulated) / clip(count,1) ------------
    float o = out[(size_t)row * DD + lane];
    {
        float cc = pcnt[row] + pcnt[NROWS + row]
                 + pcnt[2 * NROWS + row] + pcnt[3 * NROWS + row];
        if (cc < 1.f) cc = 1.f;
        o /= cc;
    }

    // ---- load row scores -> order-preserving uint keys (64 VGPRs) -----------
    unsigned int key[64];
    {
        const float4* sg = reinterpret_cast<const float4*>(ws) + (size_t)row * (LL / 4);
        #pragma unroll
        for (int i = 0; i < 16; ++i) {
            float4 f = sg[lane + 64 * i];
            float vals[4] = { f.x, f.y, f.z, f.w };
            #pragma unroll
            for (int c = 0; c < 4; ++c) {
                unsigned int u = __float_as_uint(vals[c]);
                key[4 * i + c] = ((int)u < 0) ? ~u : (u | 0x80000000u);
            }
        }
    }

    // ---- 4-pass radix select: exact 32nd-largest key + tie quota ------------
    unsigned int prefix = 0, quota = KEEP;
    #pragma unroll
    for (int pass = 0; pass < 4; ++pass) {
        const int shift = 24 - 8 * pass;
        const unsigned int hs = (pass == 0) ? 0u : (unsigned int)(32 - 8 * pass);
        reinterpret_cast<uint4*>(hist[wave])[lane] = make_uint4(0u, 0u, 0u, 0u);
        __asm__ volatile("s_waitcnt lgkmcnt(0)" ::: "memory");
        #pragma unroll
        for (int e = 0; e < 64; ++e) {
            bool act = (pass == 0) || ((key[e] >> hs) == prefix);
            if (act) atomicAdd(&hist[wave][(key[e] >> shift) & 255u], 1u);
        }
        __asm__ volatile("s_waitcnt lgkmcnt(0)" ::: "memory");
        uint4 h = reinterpret_cast<const uint4*>(hist[wave])[lane];
        unsigned int s4  = h.x + h.y + h.z + h.w;
        unsigned int suf = s4;
        #pragma unroll
        for (int off = 1; off < 64; off <<= 1) {
            unsigned int v = (unsigned int)__shfl_down((int)suf, off);
            if (lane + off < 64) suf += v;
        }
        unsigned int above = suf - s4;
        bool cond = (suf >= quota) && (above < quota);
        unsigned int Bq = 0, nq = 0;
        if (cond) {
            unsigned int hb[4] = { h.x, h.y, h.z, h.w };
            unsigned int run = above;
            int Bj = 0;
            #pragma unroll
            for (int j = 3; j >= 0; --j) {
                unsigned int nb = run + hb[j];
                if (nb >= quota) { Bj = j; break; }
                run = nb;
            }
            Bq = (unsigned int)(lane * 4 + Bj);
            nq = quota - run;
        }
        unsigned long long bal = __ballot(cond);
        int src = __ffsll(bal) - 1;
        Bq = (unsigned int)__shfl((int)Bq, src);
        nq = (unsigned int)__shfl((int)nq, src);
        prefix = (prefix << 8) | Bq;
        quota  = nq;
    }
    const unsigned int T = prefix;
    const bool take_eq = (T != MASKED_KEY);

    // ---- compact selected (val,idx) into LDS --------------------------------
    if (lane < KEEP) { wsel[wave][lane] = 0.f; selIdx[wave][lane] = 0; }
    if (lane == 0)   { selCnt[wave] = 0; eqCnt[wave] = 0; }
    __asm__ volatile("s_waitcnt lgkmcnt(0)" ::: "memory");
    #pragma unroll
    for (int e = 0; e < 64; ++e) {
        unsigned int k = key[e];
        if (k > T) {
            int slot = atomicAdd(&selCnt[wave], 1);
            selKey[wave][slot] = k;
            selIdx[wave][slot] = 256 * (e >> 2) + 4 * lane + (e & 3);
        } else if (take_eq && k == T) {
            int t2 = atomicAdd(&eqCnt[wave], 1);
            if (t2 < (int)quota) {
                int slot = atomicAdd(&selCnt[wave], 1);
                selKey[wave][slot] = k;
                selIdx[wave][slot] = 256 * (e >> 2) + 4 * lane + (e & 3);
            }
        }
    }
    __asm__ volatile("s_waitcnt lgkmcnt(0)" ::: "memory");
    const int S = selCnt[wave];

    // ---- softmax over selected + padded static gather -----------------------
    if (S > 0) {
        float vj = -FLT_MAX;
        if (lane < S) {
            unsigned int kk = selKey[wave][lane];
            unsigned int u = (kk & 0x80000000u) ? (kk ^ 0x80000000u) : ~kk;
            vj = __uint_as_float(u);
        }
        float mx = vj;
        #pragma unroll
        for (int off = 1; off < 64; off <<= 1) mx = fmaxf(mx, __shfl_xor(mx, off));
        float e = (lane < S) ? expf(vj - mx) : 0.f;
        float sum = e;
        #pragma unroll
        for (int off = 1; off < 64; off <<= 1) sum += __shfl_xor(sum, off);
        if (lane < S) wsel[wave][lane] = e / sum;
        __asm__ volatile("s_waitcnt lgkmcnt(0)" ::: "memory");
        const float* vb = vmat + (size_t)b * LL * DD + lane;
        #pragma unroll
        for (int j = 0; j < KEEP; ++j) {
            float wj = wsel[wave][j];
            int   ij = selIdx[wave][j];
            o += wj * vb[(size_t)ij * DD];
        }
    }
    out[(size_t)row * DD + lane] = o;
}

// ============================================================================
// Fallback (proven round-1 monolith) in case ws_size < WS_TOTAL*4.
// ============================================================================
#define QT   2
#define NT   256
#define NTILES (LL / NT)

__global__ __launch_bounds__(NT, 4) void ga_fused_fb(
    const float* __restrict__ q, const float* __restrict__ kmat,
    const float* __restrict__ vmat, const int* __restrict__ mask,
    float* __restrict__ out)
{
    __shared__ float sc[QT][LL];
    __shared__ float q_s[QT][DD];
    __shared__ unsigned long long mbits[QT][LL / 64];
    __shared__ float redv[4][QT][DD];
    __shared__ float mean_s[QT][DD];
    __shared__ int   count_s[QT];
    __shared__ int   sel_idx[QT][KEEP];
    __shared__ float sel_val[QT][KEEP];
    __shared__ int   sel_cnt[QT];
    __shared__ float wred[4];
    __shared__ int   ired[4];
    __shared__ int   brk;
    __shared__ float wgt[QT][KEEP];

    const int t = threadIdx.x, wave = t >> 6, lane = t & 63;
    const int n0 = blockIdx.x * QT, b = n0 / LQ;

    if (t < QT) sel_cnt[t] = 0;
    if (t < QT * DD) q_s[t >> 6][t & 63] = q[(size_t)(n0 + (t >> 6)) * DD + (t & 63)];
    __syncthreads();

    const float4* q4_0 = reinterpret_cast<const float4*>(&q_s[0][0]);
    const float4* q4_1 = reinterpret_cast<const float4*>(&q_s[1][0]);
    for (int tile = 0; tile < NTILES; ++tile) {
        int l = tile * NT + t;
        const float4* kr = reinterpret_cast<const float4*>(kmat + (size_t)(b * LL + l) * DD);
        float d0 = 0.f, d1 = 0.f;
        #pragma unroll
        for (int i = 0; i < 16; ++i) {
            float4 kk = kr[i], qa = q4_0[i], qb = q4_1[i];
            d0 += kk.x * qa.x + kk.y * qa.y + kk.z * qa.z + kk.w * qa.w;
            d1 += kk.x * qb.x + kk.y * qb.y + kk.z * qb.z + kk.w * qb.w;
        }
        int mv0 = mask[(size_t)n0 * LL + l];
        int mv1 = mask[(size_t)(n0 + 1) * LL + l];
        unsigned long long b0 = __ballot(mv0 != 0);
        unsigned long long b1 = __ballot(mv1 != 0);
        if (lane == 0) { mbits[0][tile * 4 + wave] = b0; mbits[1][tile * 4 + wave] = b1; }
        sc[0][l] = mv0 ? d0 * 0.125f : -FLT_MAX;
        sc[1][l] = mv1 ? d1 * 0.125f : -FLT_MAX;
    }
    __syncthreads();

    if (wave < QT) {
        int c = (int)__popcll(mbits[wave][lane]);
        for (int off = 32; off >= 1; off >>= 1) c += __shfl_down(c, off);
        if (lane == 0) count_s[wave] = c;
    }
    {
        float acc0 = 0.f, acc1 = 0.f;
        const int g = wave, d = lane;
        for (int wi = 0; wi < LL / 64; ++wi) {
            unsigned long long w0 = mbits[0][wi], w1 = mbits[1][wi];
            const float* vp = vmat + (size_t)(b * LL + wi * 64 + g) * DD + d;
            #pragma unroll 4
            for (int ii = 0; ii < 16; ++ii) {
                int sh = g + 4 * ii;
                float vv = vp[(size_t)(4 * ii) * DD];
                if ((w0 >> sh) & 1ULL) acc0 += vv;
                if ((w1 >> sh) & 1ULL) acc1 += vv;
            }
        }
        redv[g][0][d] = acc0; redv[g][1][d] = acc1;
    }
    __syncthreads();
    if (t < QT * DD) {
        int qt = t >> 6, dd = t & 63;
        float s2 = redv[0][qt][dd] + redv[1][qt][dd] + redv[2][qt][dd] + redv[3][qt][dd];
        int c = count_s[qt]; if (c < 1) c = 1;
        mean_s[qt][dd] = s2 / (float)c;
    }
    __syncthreads();

    for (int qt = 0; qt < QT; ++qt) {
        for (int s = 0; s < KEEP; ++s) {
            float m = -FLT_MAX; int mi = LL;
            for (int j = 0; j < NTILES; ++j) {
                int l = j * NT + t;
                float val = sc[qt][l];
                if (val > m) { m = val; mi = l; }
            }
            for (int off = 32; off >= 1; off >>= 1) {
                float ov = __shfl_down(m, off);
                int   oi = __shfl_down(mi, off);
                if (ov > m || (ov == m && oi < mi)) { m = ov; mi = oi; }
            }
            if (lane == 0) { wred[wave] = m; ired[wave] = mi; }
            __syncthreads();
            if (t == 0) {
                float bv = wred[0]; int bi = ired[0];
                for (int w2 = 1; w2 < 4; ++w2) {
                    float ov = wred[w2]; int oi = ired[w2];
                    if (ov > bv || (ov == bv && oi < bi)) { bv = ov; bi = oi; }
                }
                if (bv > -FLT_MAX) {
                    sel_idx[qt][s] = bi; sel_val[qt][s] = bv; sel_cnt[qt] = s + 1;
                    sc[qt][bi] = -FLT_MAX; brk = 0;
                } else brk = 1;
            }
            __syncthreads();
            if (brk) break;
        }
    }

    if (wave < QT) {
        int qt = wave, S = sel_cnt[qt];
        if (S > 0) {
            float mx = sel_val[qt][0];
            float e = 0.f;
            if (lane < S) e = expf(sel_val[qt][lane] - mx);
            float ssum = e;
            for (int off = 32; off >= 1; off >>= 1) ssum += __shfl_xor(ssum, off);
            if (lane < S) wgt[qt][lane] = e / ssum;
        }
    }
    __syncthreads();
    if (wave < QT) {
        int qt = wave, S = sel_cnt[qt];
        float o = mean_s[qt][lane];
        for (int j = 0; j < S; ++j)
            o += wgt[qt][j] * vmat[(size_t)(b * LL + sel_idx[qt][j]) * DD + lane];
        out[(size_t)(n0 + qt) * DD + lane] = o;
    }
}

// ============================================================================
extern "C" void kernel_launch(void* const* d_in, const int* in_sizes, int n_in,
                              void* d_out, int out_size, void* d_ws, size_t ws_size,
                              hipStream_t stream) {
    const float* q    = (const float*)d_in[0];
    const float* kmat = (const float*)d_in[1];
    const float* vmat = (const float*)d_in[2];
    const int*   mask = (const int*)d_in[3];
    float* out = (float*)d_out;

    const size_t need = (size_t)WS_TOTAL * sizeof(float);   // 71.37 MB (== proven)
    if (ws_size >= need) {
        float* ws = (float*)d_ws;
        unsigned short* vt = (unsigned short*)(ws + WS_VT);
        float* pcnt = ws + WS_PC;
        hipMemsetAsync(out, 0, (size_t)NROWS * DD * sizeof(float), stream);
        hipLaunchKernelGGL(k_scores, dim3(4096), dim3(256), 0, stream,
                           q, kmat, mask, ws);
        hipLaunchKernelGGL(k_vt, dim3(NB * 16), dim3(256), 0, stream, vmat, vt);
        hipLaunchKernelGGL(k_mean, dim3((NROWS / 16) * 4), dim3(256), 0, stream,
                           mask, vt, out, pcnt);
        hipLaunchKernelGGL(k_select, dim3(NROWS / 4), dim3(256), 0, stream,
                           vmat, ws, pcnt, out);
    } else {
        hipLaunchKernelGGL(ga_fused_fb, dim3(NROWS / QT), dim3(NT), 0, stream,
                           q, kmat, vmat, mask, out);
    }
}

// Round 10
// 253.647 us; speedup vs baseline: 1.6837x; 1.0004x over previous
//
#include <hip/hip_runtime.h>
#include <float.h>
#include <math.h>

// Problem constants (from reference setup_inputs)
#define LQ   512
#define LL   4096      // key length
#define DD   64        // d_qk == d_v
#define KEEP 32        // MAX_SET_SIZE
#define NB   8         // batches
#define NROWS (NB * LQ)    // 4096 flat query rows

// ---- ws layout (floats) -----------------------------------------------------
// scores : [NROWS][LL] fp32                67.11 MB
// VT     : [NB][DD][LL] bf16                4.19 MB
// pcnt   : [NROWS] fp32 counts (atomic)     0.02 MB (region sized 4x, proven)
#define WS_VT    (NROWS * LL)                    // 16,777,216
#define WS_PC    (WS_VT + (NB * DD * LL) / 2)    // 17,825,792
#define WS_TOTAL (WS_PC + 4 * NROWS)             // 17,842,176 floats = 71.37 MB

#define MASKED_KEY 0x00800000u              // order-key of -FLT_MAX

typedef short  bf16x8 __attribute__((ext_vector_type(8)));
typedef float  f32x4  __attribute__((ext_vector_type(4)));

__device__ __forceinline__ float dot4(float4 a, float4 b) {
    return a.x * b.x + a.y * b.y + a.z * b.z + a.w * b.w;
}
__device__ __forceinline__ unsigned short f2bf(float f) {
    unsigned int u = __float_as_uint(f);
    return (unsigned short)((u + 0x7FFFu + ((u >> 16) & 1u)) >> 16);   // RNE
}

// ============================================================================
// P0: v[b][l][d] fp32 -> VT[b][d][l] bf16 (LDS tile transpose). UNCHANGED R1.
// Runs BEFORE k_scores now (k_scores consumes VT for the fused mean).
// ============================================================================
#define TP_LB 256
__global__ __launch_bounds__(256) void k_vt(
    const float* __restrict__ v, unsigned short* __restrict__ vt)
{
    __shared__ unsigned short tile[DD][TP_LB + 8];   // +8 ushorts: bank de-phase
    const int t  = threadIdx.x;
    const int b  = blockIdx.x >> 4;                  // 16 blocks per batch
    const int l0 = (blockIdx.x & 15) * TP_LB;

    const float4* vg = reinterpret_cast<const float4*>(v + ((size_t)b * LL + l0) * DD);
    #pragma unroll
    for (int i = 0; i < 16; ++i) {
        int j = t + 256 * i;                         // f4 index: l = j>>4, dq = (j&15)*4
        float4 f = vg[j];
        int l = j >> 4, dq = (j & 15) * 4;
        tile[dq + 0][l] = f2bf(f.x);
        tile[dq + 1][l] = f2bf(f.y);
        tile[dq + 2][l] = f2bf(f.z);
        tile[dq + 3][l] = f2bf(f.w);
    }
    __syncthreads();
    const int d = t >> 2, seg = t & 3;               // 64 ushorts per thread
    const uint4* src = reinterpret_cast<const uint4*>(&tile[d][seg * 64]);
    uint4* dst = reinterpret_cast<uint4*>(vt + ((size_t)b * DD + d) * LL + l0 + seg * 64);
    #pragma unroll
    for (int i = 0; i < 8; ++i) dst[i] = src[i];
}

// ============================================================================
// K1 v3: register-K scores + FUSED masked-mean partial.
// Scoring part byte-identical to R9 (70us, verified): lane = one l-column,
// K row in 16 float4 VGPRs, q via wave-uniform scalar loads, masked store.
// Mean fusion: the wave already holds mask dwords for 16 rows x its 64 l.
// ballot -> 64-bit row masks -> LDS -> per-lane byte -> exact 0/1 bf16 afrag;
// B = VT fragment (L2-resident, k_mean's verified pattern); 2 K-steps x 4
// d-tiles = 8 MFMA; block-level LDS reduce; atomicAdd 16x64 partial into
// ZEROED out + counts into pcnt (R8 scheme, 16 l-chunks contribute).
// This deletes k_mean and its 67 MB second mask read.
// ============================================================================
__global__ __launch_bounds__(256) void k_scores(
    const float* __restrict__ q,
    const float* __restrict__ kmat,
    const int*   __restrict__ mask,
    const unsigned short* __restrict__ vt,
    float*       __restrict__ ws_sc,
    float*       __restrict__ out,
    float*       __restrict__ pcnt)
{
    __shared__ unsigned long long bits64[4][16];     // [wave][row] 512 B
    __shared__ float sums[4][4][16][16];             // [wave][dtile][row][col] 16 KB
    __shared__ float cnt_s[4][16];

    const int t    = threadIdx.x;
    const int wave = t >> 6;
    const int lane = t & 63;
    const int lc   = blockIdx.x & 15;                // l-chunk -> XCD spread (%8)
    const int rg   = blockIdx.x >> 4;                // row-group 0..255
    const int n0   = rg * 16;
    const int b    = n0 / LQ;
    const int l    = lc * 256 + wave * 64 + lane;    // this lane's l

    // ---- mask prefetch: 16 rows, coalesced dword each -----------------------
    int mreg[16];
    #pragma unroll
    for (int p = 0; p < 16; ++p)
        mreg[p] = mask[(size_t)(n0 + p) * LL + l];

    // ---- ballots -> per-row 64-bit masks of this wave's 64 l ---------------
    unsigned long long bl[16];
    #pragma unroll
    for (int p = 0; p < 16; ++p) bl[p] = __ballot(mreg[p] != 0);
    if (lane == 0) {
        #pragma unroll
        for (int p = 0; p < 16; ++p) bits64[wave][p] = bl[p];
    }
    __asm__ volatile("s_waitcnt lgkmcnt(0)" ::: "memory");

    // ---- fused mean partial: 8 MFMA off LDS bits + VT ----------------------
    {
        const int row_a = lane & 15;                 // MFMA m / B n index
        const int chunk = lane >> 4;                 // k-quad
        const unsigned char* bb =
            reinterpret_cast<const unsigned char*>(&bits64[wave][row_a]);
        const unsigned short* vtb =
            vt + (size_t)b * DD * LL + lc * 256 + wave * 64 + chunk * 8;

        f32x4 acc[4];
        #pragma unroll
        for (int dt = 0; dt < 4; ++dt) acc[dt] = (f32x4){0.f, 0.f, 0.f, 0.f};

        #pragma unroll
        for (int s = 0; s < 2; ++s) {                // K-step: 32 l each
            const unsigned int byte = bb[s * 4 + chunk];
            unsigned int pk[4];
            pk[0] = ((byte & 1u)   ? 0x3F80u : 0u) | ((byte & 2u)   ? 0x3F800000u : 0u);
            pk[1] = ((byte & 4u)   ? 0x3F80u : 0u) | ((byte & 8u)   ? 0x3F800000u : 0u);
            pk[2] = ((byte & 16u)  ? 0x3F80u : 0u) | ((byte & 32u)  ? 0x3F800000u : 0u);
            pk[3] = ((byte & 64u)  ? 0x3F80u : 0u) | ((byte & 128u) ? 0x3F800000u : 0u);
            bf16x8 afrag = *reinterpret_cast<bf16x8*>(pk);
            #pragma unroll
            for (int dt = 0; dt < 4; ++dt) {
                bf16x8 bfrag = *reinterpret_cast<const bf16x8*>(
                    vtb + (size_t)(dt * 16 + row_a) * LL + s * 32);
                acc[dt] = __builtin_amdgcn_mfma_f32_16x16x32_bf16(afrag, bfrag, acc[dt], 0, 0, 0);
            }
        }
        #pragma unroll
        for (int dt = 0; dt < 4; ++dt)
            #pragma unroll
            for (int r = 0; r < 4; ++r)
                sums[wave][dt][chunk * 4 + r][row_a] = acc[dt][r];
        if (lane < 16)
            cnt_s[wave][lane] = (float)__popcll(bits64[wave][lane]);
    }
    __syncthreads();

    // ---- combine 4 waves + atomic partial accumulate ------------------------
    {
        const int d = t & 63, rgrp = t >> 6;
        #pragma unroll
        for (int rr = 0; rr < 4; ++rr) {
            const int row = rgrp * 4 + rr;
            float s = sums[0][d >> 4][row][d & 15] + sums[1][d >> 4][row][d & 15]
                    + sums[2][d >> 4][row][d & 15] + sums[3][d >> 4][row][d & 15];
            atomicAdd(&out[(size_t)(n0 + row) * DD + d], s);
        }
        if (t < 16) {
            float c = cnt_s[0][t] + cnt_s[1][t] + cnt_s[2][t] + cnt_s[3][t];
            atomicAdd(&pcnt[n0 + t], c);
        }
    }

    // ---- scoring: register-K, R9 proven form --------------------------------
    const float4* kr = reinterpret_cast<const float4*>(kmat + ((size_t)b * LL + l) * DD);
    float4 kreg[16];
    #pragma unroll
    for (int i = 0; i < 16; ++i) kreg[i] = kr[i];

    const int qb = __builtin_amdgcn_readfirstlane(n0 * DD);
    #pragma unroll
    for (int p = 0; p < 16; ++p) {
        const float4* qp = reinterpret_cast<const float4*>(q + qb + p * DD);
        float ax = 0.f, ay = 0.f, az = 0.f, aw = 0.f;
        #pragma unroll
        for (int i = 0; i < 16; ++i) {
            float4 qv = qp[i];                       // wave-uniform -> s_load
            ax = fmaf(qv.x, kreg[i].x, ax);
            ay = fmaf(qv.y, kreg[i].y, ay);
            az = fmaf(qv.z, kreg[i].z, az);
            aw = fmaf(qv.w, kreg[i].w, aw);
        }
        float acc = ax + ay + az + aw;
        ws_sc[(size_t)(n0 + p) * LL + l] = mreg[p] ? acc * 0.125f : -FLT_MAX;
    }
}

// ============================================================================
// K2: per-wave exact radix top-32 — R8 form; mean finalize now reads the
// single atomic pcnt strip.
// ============================================================================
__global__ __launch_bounds__(256, 3) void k_select(
    const float* __restrict__ vmat,
    const float* __restrict__ ws,
    const float* __restrict__ pcnt,
    float*       __restrict__ out)
{
    __shared__ unsigned int hist[4][256];
    __shared__ unsigned int selKey[4][KEEP];
    __shared__ int          selIdx[4][KEEP];
    __shared__ float        wsel[4][KEEP];
    __shared__ int          selCnt[4], eqCnt[4];

    const int t    = threadIdx.x;
    const int wave = t >> 6;
    const int lane = t & 63;
    const int row  = blockIdx.x * 4 + wave;
    const int b    = row / LQ;

    // ---- mean finalize: sum (atomic-accumulated) / clip(count,1) ------------
    float o = out[(size_t)row * DD + lane];
    {
        float cc = pcnt[row];
        if (cc < 1.f) cc = 1.f;
        o /= cc;
    }

    // ---- load row scores -> order-preserving uint keys (64 VGPRs) -----------
    unsigned int key[64];
    {
        const float4* sg = reinterpret_cast<const float4*>(ws) + (size_t)row * (LL / 4);
        #pragma unroll
        for (int i = 0; i < 16; ++i) {
            float4 f = sg[lane + 64 * i];
            float vals[4] = { f.x, f.y, f.z, f.w };
            #pragma unroll
            for (int c = 0; c < 4; ++c) {
                unsigned int u = __float_as_uint(vals[c]);
                key[4 * i + c] = ((int)u < 0) ? ~u : (u | 0x80000000u);
            }
        }
    }

    // ---- 4-pass radix select: exact 32nd-largest key + tie quota ------------
    unsigned int prefix = 0, quota = KEEP;
    #pragma unroll
    for (int pass = 0; pass < 4; ++pass) {
        const int shift = 24 - 8 * pass;
        const unsigned int hs = (pass == 0) ? 0u : (unsigned int)(32 - 8 * pass);
        reinterpret_cast<uint4*>(hist[wave])[lane] = make_uint4(0u, 0u, 0u, 0u);
        __asm__ volatile("s_waitcnt lgkmcnt(0)" ::: "memory");
        #pragma unroll
        for (int e = 0; e < 64; ++e) {
            bool act = (pass == 0) || ((key[e] >> hs) == prefix);
            if (act) atomicAdd(&hist[wave][(key[e] >> shift) & 255u], 1u);
        }
        __asm__ volatile("s_waitcnt lgkmcnt(0)" ::: "memory");
        uint4 h = reinterpret_cast<const uint4*>(hist[wave])[lane];
        unsigned int s4  = h.x + h.y + h.z + h.w;
        unsigned int suf = s4;
        #pragma unroll
        for (int off = 1; off < 64; off <<= 1) {
            unsigned int v = (unsigned int)__shfl_down((int)suf, off);
            if (lane + off < 64) suf += v;
        }
        unsigned int above = suf - s4;
        bool cond = (suf >= quota) && (above < quota);
        unsigned int Bq = 0, nq = 0;
        if (cond) {
            unsigned int hb[4] = { h.x, h.y, h.z, h.w };
            unsigned int run = above;
            int Bj = 0;
            #pragma unroll
            for (int j = 3; j >= 0; --j) {
                unsigned int nb = run + hb[j];
                if (nb >= quota) { Bj = j; break; }
                run = nb;
            }
            Bq = (unsigned int)(lane * 4 + Bj);
            nq = quota - run;
        }
        unsigned long long bal = __ballot(cond);
        int src = __ffsll(bal) - 1;
        Bq = (unsigned int)__shfl((int)Bq, src);
        nq = (unsigned int)__shfl((int)nq, src);
        prefix = (prefix << 8) | Bq;
        quota  = nq;
    }
    const unsigned int T = prefix;
    const bool take_eq = (T != MASKED_KEY);

    // ---- compact selected (val,idx) into LDS --------------------------------
    if (lane < KEEP) { wsel[wave][lane] = 0.f; selIdx[wave][lane] = 0; }
    if (lane == 0)   { selCnt[wave] = 0; eqCnt[wave] = 0; }
    __asm__ volatile("s_waitcnt lgkmcnt(0)" ::: "memory");
    #pragma unroll
    for (int e = 0; e < 64; ++e) {
        unsigned int k = key[e];
        if (k > T) {
            int slot = atomicAdd(&selCnt[wave], 1);
            selKey[wave][slot] = k;
            selIdx[wave][slot] = 256 * (e >> 2) + 4 * lane + (e & 3);
        } else if (take_eq && k == T) {
            int t2 = atomicAdd(&eqCnt[wave], 1);
            if (t2 < (int)quota) {
                int slot = atomicAdd(&selCnt[wave], 1);
                selKey[wave][slot] = k;
                selIdx[wave][slot] = 256 * (e >> 2) + 4 * lane + (e & 3);
            }
        }
    }
    __asm__ volatile("s_waitcnt lgkmcnt(0)" ::: "memory");
    const int S = selCnt[wave];

    // ---- softmax over selected + padded static gather -----------------------
    if (S > 0) {
        float vj = -FLT_MAX;
        if (lane < S) {
            unsigned int kk = selKey[wave][lane];
            unsigned int u = (kk & 0x80000000u) ? (kk ^ 0x80000000u) : ~kk;
            vj = __uint_as_float(u);
        }
        float mx = vj;
        #pragma unroll
        for (int off = 1; off < 64; off <<= 1) mx = fmaxf(mx, __shfl_xor(mx, off));
        float e = (lane < S) ? expf(vj - mx) : 0.f;
        float sum = e;
        #pragma unroll
        for (int off = 1; off < 64; off <<= 1) sum += __shfl_xor(sum, off);
        if (lane < S) wsel[wave][lane] = e / sum;
        __asm__ volatile("s_waitcnt lgkmcnt(0)" ::: "memory");
        const float* vb = vmat + (size_t)b * LL * DD + lane;
        #pragma unroll
        for (int j = 0; j < KEEP; ++j) {
            float wj = wsel[wave][j];
            int   ij = selIdx[wave][j];
            o += wj * vb[(size_t)ij * DD];
        }
    }
    out[(size_t)row * DD + lane] = o;
}

// ============================================================================
// Fallback (proven round-1 monolith) in case ws_size < WS_TOTAL*4.
// ============================================================================
#define QT   2
#define NT   256
#define NTILES (LL / NT)

__global__ __launch_bounds__(NT, 4) void ga_fused_fb(
    const float* __restrict__ q, const float* __restrict__ kmat,
    const float* __restrict__ vmat, const int* __restrict__ mask,
    float* __restrict__ out)
{
    __shared__ float sc[QT][LL];
    __shared__ float q_s[QT][DD];
    __shared__ unsigned long long mbits[QT][LL / 64];
    __shared__ float redv[4][QT][DD];
    __shared__ float mean_s[QT][DD];
    __shared__ int   count_s[QT];
    __shared__ int   sel_idx[QT][KEEP];
    __shared__ float sel_val[QT][KEEP];
    __shared__ int   sel_cnt[QT];
    __shared__ float wred[4];
    __shared__ int   ired[4];
    __shared__ int   brk;
    __shared__ float wgt[QT][KEEP];

    const int t = threadIdx.x, wave = t >> 6, lane = t & 63;
    const int n0 = blockIdx.x * QT, b = n0 / LQ;

    if (t < QT) sel_cnt[t] = 0;
    if (t < QT * DD) q_s[t >> 6][t & 63] = q[(size_t)(n0 + (t >> 6)) * DD + (t & 63)];
    __syncthreads();

    const float4* q4_0 = reinterpret_cast<const float4*>(&q_s[0][0]);
    const float4* q4_1 = reinterpret_cast<const float4*>(&q_s[1][0]);
    for (int tile = 0; tile < NTILES; ++tile) {
        int l = tile * NT + t;
        const float4* kr = reinterpret_cast<const float4*>(kmat + (size_t)(b * LL + l) * DD);
        float d0 = 0.f, d1 = 0.f;
        #pragma unroll
        for (int i = 0; i < 16; ++i) {
            float4 kk = kr[i], qa = q4_0[i], qb = q4_1[i];
            d0 += kk.x * qa.x + kk.y * qa.y + kk.z * qa.z + kk.w * qa.w;
            d1 += kk.x * qb.x + kk.y * qb.y + kk.z * qb.z + kk.w * qb.w;
        }
        int mv0 = mask[(size_t)n0 * LL + l];
        int mv1 = mask[(size_t)(n0 + 1) * LL + l];
        unsigned long long b0 = __ballot(mv0 != 0);
        unsigned long long b1 = __ballot(mv1 != 0);
        if (lane == 0) { mbits[0][tile * 4 + wave] = b0; mbits[1][tile * 4 + wave] = b1; }
        sc[0][l] = mv0 ? d0 * 0.125f : -FLT_MAX;
        sc[1][l] = mv1 ? d1 * 0.125f : -FLT_MAX;
    }
    __syncthreads();

    if (wave < QT) {
        int c = (int)__popcll(mbits[wave][lane]);
        for (int off = 32; off >= 1; off >>= 1) c += __shfl_down(c, off);
        if (lane == 0) count_s[wave] = c;
    }
    {
        float acc0 = 0.f, acc1 = 0.f;
        const int g = wave, d = lane;
        for (int wi = 0; wi < LL / 64; ++wi) {
            unsigned long long w0 = mbits[0][wi], w1 = mbits[1][wi];
            const float* vp = vmat + (size_t)(b * LL + wi * 64 + g) * DD + d;
            #pragma unroll 4
            for (int ii = 0; ii < 16; ++ii) {
                int sh = g + 4 * ii;
                float vv = vp[(size_t)(4 * ii) * DD];
                if ((w0 >> sh) & 1ULL) acc0 += vv;
                if ((w1 >> sh) & 1ULL) acc1 += vv;
            }
        }
        redv[g][0][d] = acc0; redv[g][1][d] = acc1;
    }
    __syncthreads();
    if (t < QT * DD) {
        int qt = t >> 6, dd = t & 63;
        float s2 = redv[0][qt][dd] + redv[1][qt][dd] + redv[2][qt][dd] + redv[3][qt][dd];
        int c = count_s[qt]; if (c < 1) c = 1;
        mean_s[qt][dd] = s2 / (float)c;
    }
    __syncthreads();

    for (int qt = 0; qt < QT; ++qt) {
        for (int s = 0; s < KEEP; ++s) {
            float m = -FLT_MAX; int mi = LL;
            for (int j = 0; j < NTILES; ++j) {
                int l = j * NT + t;
                float val = sc[qt][l];
                if (val > m) { m = val; mi = l; }
            }
            for (int off = 32; off >= 1; off >>= 1) {
                float ov = __shfl_down(m, off);
                int   oi = __shfl_down(mi, off);
                if (ov > m || (ov == m && oi < mi)) { m = ov; mi = oi; }
            }
            if (lane == 0) { wred[wave] = m; ired[wave] = mi; }
            __syncthreads();
            if (t == 0) {
                float bv = wred[0]; int bi = ired[0];
                for (int w2 = 1; w2 < 4; ++w2) {
                    float ov = wred[w2]; int oi = ired[w2];
                    if (ov > bv || (ov == bv && oi < bi)) { bv = ov; bi = oi; }
                }
                if (bv > -FLT_MAX) {
                    sel_idx[qt][s] = bi; sel_val[qt][s] = bv; sel_cnt[qt] = s + 1;
                    sc[qt][bi] = -FLT_MAX; brk = 0;
                } else brk = 1;
            }
            __syncthreads();
            if (brk) break;
        }
    }

    if (wave < QT) {
        int qt = wave, S = sel_cnt[qt];
        if (S > 0) {
            float mx = sel_val[qt][0];
            float e = 0.f;
            if (lane < S) e = expf(sel_val[qt][lane] - mx);
            float ssum = e;
            for (int off = 32; off >= 1; off >>= 1) ssum += __shfl_xor(ssum, off);
            if (lane < S) wgt[qt][lane] = e / ssum;
        }
    }
    __syncthreads();
    if (wave < QT) {
        int qt = wave, S = sel_cnt[qt];
        float o = mean_s[qt][lane];
        for (int j = 0; j < S; ++j)
            o += wgt[qt][j] * vmat[(size_t)(b * LL + sel_idx[qt][j]) * DD + lane];
        out[(size_t)(n0 + qt) * DD + lane] = o;
    }
}

// ============================================================================
extern "C" void kernel_launch(void* const* d_in, const int* in_sizes, int n_in,
                              void* d_out, int out_size, void* d_ws, size_t ws_size,
                              hipStream_t stream) {
    const float* q    = (const float*)d_in[0];
    const float* kmat = (const float*)d_in[1];
    const float* vmat = (const float*)d_in[2];
    const int*   mask = (const int*)d_in[3];
    float* out = (float*)d_out;

    const size_t need = (size_t)WS_TOTAL * sizeof(float);   // 71.37 MB (== proven)
    if (ws_size >= need) {
        float* ws = (float*)d_ws;
        unsigned short* vt = (unsigned short*)(ws + WS_VT);
        float* pcnt = ws + WS_PC;
        hipMemsetAsync(out, 0, (size_t)NROWS * DD * sizeof(float), stream);
        hipMemsetAsync(pcnt, 0, (size_t)NROWS * sizeof(float), stream);
        hipLaunchKernelGGL(k_vt, dim3(NB * 16), dim3(256), 0, stream, vmat, vt);
        hipLaunchKernelGGL(k_scores, dim3(4096), dim3(256), 0, stream,
                           q, kmat, mask, vt, ws, out, pcnt);
        hipLaunchKernelGGL(k_select, dim3(NROWS / 4), dim3(256), 0, stream,
                           vmat, ws, pcnt, out);
    } else {
        hipLaunchKernelGGL(ga_fused_fb, dim3(NROWS / QT), dim3(NT), 0, stream,
                           q, kmat, vmat, mask, out);
    }
}

// Round 11
// 248.964 us; speedup vs baseline: 1.7154x; 1.0188x over previous
//
#include <hip/hip_runtime.h>
#include <float.h>
#include <math.h>

// Problem constants (from reference setup_inputs)
#define LQ   512
#define LL   4096      // key length
#define DD   64        // d_qk == d_v
#define KEEP 32        // MAX_SET_SIZE
#define NB   8         // batches
#define NROWS (NB * LQ)    // 4096 flat query rows

// ---- ws layout (floats) -----------------------------------------------------
// scores : [NROWS][LL] fp32                67.11 MB
// VT     : [NB][DD][LL] bf16                4.19 MB
// pcnt   : [NROWS] fp32 counts (atomic)     0.02 MB (region sized 4x, proven)
#define WS_VT    (NROWS * LL)                    // 16,777,216
#define WS_PC    (WS_VT + (NB * DD * LL) / 2)    // 17,825,792
#define WS_TOTAL (WS_PC + 4 * NROWS)             // 17,842,176 floats = 71.37 MB

#define MASKED_KEY 0x00800000u              // order-key of -FLT_MAX

typedef short  bf16x8 __attribute__((ext_vector_type(8)));
typedef float  f32x4  __attribute__((ext_vector_type(4)));

__device__ __forceinline__ float dot4(float4 a, float4 b) {
    return a.x * b.x + a.y * b.y + a.z * b.z + a.w * b.w;
}
__device__ __forceinline__ unsigned short f2bf(float f) {
    unsigned int u = __float_as_uint(f);
    return (unsigned short)((u + 0x7FFFu + ((u >> 16) & 1u)) >> 16);   // RNE
}

// ============================================================================
// P0: v[b][l][d] fp32 -> VT[b][d][l] bf16 (LDS tile transpose) + ZERO out and
// pcnt (absorbs the two hipMemsetAsync nodes: 5 graph nodes -> 3). Zeroing
// is 2 float4 + <=32 B of stores per block -- free. k_vt completes before
// k_scores (stream order), so the zeroed buffers gate the atomics correctly.
// ============================================================================
#define TP_LB 256
__global__ __launch_bounds__(256) void k_vt(
    const float* __restrict__ v, unsigned short* __restrict__ vt,
    float* __restrict__ out, float* __restrict__ pcnt)
{
    __shared__ unsigned short tile[DD][TP_LB + 8];   // +8 ushorts: bank de-phase
    const int t  = threadIdx.x;
    const int b  = blockIdx.x >> 4;                  // 16 blocks per batch
    const int l0 = (blockIdx.x & 15) * TP_LB;

    // ---- zeroing (replaces memset nodes): 128 blocks cover out + pcnt ------
    {
        float4 z4 = {0.f, 0.f, 0.f, 0.f};
        float4* oz = reinterpret_cast<float4*>(out);  // 65536 float4 total
        oz[blockIdx.x * 512 + t]       = z4;
        oz[blockIdx.x * 512 + 256 + t] = z4;
        if (t < 32) pcnt[blockIdx.x * 32 + t] = 0.f;  // 128*32 = 4096
    }

    const float4* vg = reinterpret_cast<const float4*>(v + ((size_t)b * LL + l0) * DD);
    #pragma unroll
    for (int i = 0; i < 16; ++i) {
        int j = t + 256 * i;                         // f4 index: l = j>>4, dq = (j&15)*4
        float4 f = vg[j];
        int l = j >> 4, dq = (j & 15) * 4;
        tile[dq + 0][l] = f2bf(f.x);
        tile[dq + 1][l] = f2bf(f.y);
        tile[dq + 2][l] = f2bf(f.z);
        tile[dq + 3][l] = f2bf(f.w);
    }
    __syncthreads();
    const int d = t >> 2, seg = t & 3;               // 64 ushorts per thread
    const uint4* src = reinterpret_cast<const uint4*>(&tile[d][seg * 64]);
    uint4* dst = reinterpret_cast<uint4*>(vt + ((size_t)b * DD + d) * LL + l0 + seg * 64);
    #pragma unroll
    for (int i = 0; i < 8; ++i) dst[i] = src[i];
}

// ============================================================================
// K1 v3: register-K scores + FUSED masked-mean partial. VERBATIM R10 (96us,
// proven, control).
// ============================================================================
__global__ __launch_bounds__(256) void k_scores(
    const float* __restrict__ q,
    const float* __restrict__ kmat,
    const int*   __restrict__ mask,
    const unsigned short* __restrict__ vt,
    float*       __restrict__ ws_sc,
    float*       __restrict__ out,
    float*       __restrict__ pcnt)
{
    __shared__ unsigned long long bits64[4][16];     // [wave][row] 512 B
    __shared__ float sums[4][4][16][16];             // [wave][dtile][row][col] 16 KB
    __shared__ float cnt_s[4][16];

    const int t    = threadIdx.x;
    const int wave = t >> 6;
    const int lane = t & 63;
    const int lc   = blockIdx.x & 15;                // l-chunk -> XCD spread (%8)
    const int rg   = blockIdx.x >> 4;                // row-group 0..255
    const int n0   = rg * 16;
    const int b    = n0 / LQ;
    const int l    = lc * 256 + wave * 64 + lane;    // this lane's l

    // ---- mask prefetch: 16 rows, coalesced dword each -----------------------
    int mreg[16];
    #pragma unroll
    for (int p = 0; p < 16; ++p)
        mreg[p] = mask[(size_t)(n0 + p) * LL + l];

    // ---- ballots -> per-row 64-bit masks of this wave's 64 l ---------------
    unsigned long long bl[16];
    #pragma unroll
    for (int p = 0; p < 16; ++p) bl[p] = __ballot(mreg[p] != 0);
    if (lane == 0) {
        #pragma unroll
        for (int p = 0; p < 16; ++p) bits64[wave][p] = bl[p];
    }
    __asm__ volatile("s_waitcnt lgkmcnt(0)" ::: "memory");

    // ---- fused mean partial: 8 MFMA off LDS bits + VT ----------------------
    {
        const int row_a = lane & 15;                 // MFMA m / B n index
        const int chunk = lane >> 4;                 // k-quad
        const unsigned char* bb =
            reinterpret_cast<const unsigned char*>(&bits64[wave][row_a]);
        const unsigned short* vtb =
            vt + (size_t)b * DD * LL + lc * 256 + wave * 64 + chunk * 8;

        f32x4 acc[4];
        #pragma unroll
        for (int dt = 0; dt < 4; ++dt) acc[dt] = (f32x4){0.f, 0.f, 0.f, 0.f};

        #pragma unroll
        for (int s = 0; s < 2; ++s) {                // K-step: 32 l each
            const unsigned int byte = bb[s * 4 + chunk];
            unsigned int pk[4];
            pk[0] = ((byte & 1u)   ? 0x3F80u : 0u) | ((byte & 2u)   ? 0x3F800000u : 0u);
            pk[1] = ((byte & 4u)   ? 0x3F80u : 0u) | ((byte & 8u)   ? 0x3F800000u : 0u);
            pk[2] = ((byte & 16u)  ? 0x3F80u : 0u) | ((byte & 32u)  ? 0x3F800000u : 0u);
            pk[3] = ((byte & 64u)  ? 0x3F80u : 0u) | ((byte & 128u) ? 0x3F800000u : 0u);
            bf16x8 afrag = *reinterpret_cast<bf16x8*>(pk);
            #pragma unroll
            for (int dt = 0; dt < 4; ++dt) {
                bf16x8 bfrag = *reinterpret_cast<const bf16x8*>(
                    vtb + (size_t)(dt * 16 + row_a) * LL + s * 32);
                acc[dt] = __builtin_amdgcn_mfma_f32_16x16x32_bf16(afrag, bfrag, acc[dt], 0, 0, 0);
            }
        }
        #pragma unroll
        for (int dt = 0; dt < 4; ++dt)
            #pragma unroll
            for (int r = 0; r < 4; ++r)
                sums[wave][dt][chunk * 4 + r][row_a] = acc[dt][r];
        if (lane < 16)
            cnt_s[wave][lane] = (float)__popcll(bits64[wave][lane]);
    }
    __syncthreads();

    // ---- combine 4 waves + atomic partial accumulate ------------------------
    {
        const int d = t & 63, rgrp = t >> 6;
        #pragma unroll
        for (int rr = 0; rr < 4; ++rr) {
            const int row = rgrp * 4 + rr;
            float s = sums[0][d >> 4][row][d & 15] + sums[1][d >> 4][row][d & 15]
                    + sums[2][d >> 4][row][d & 15] + sums[3][d >> 4][row][d & 15];
            atomicAdd(&out[(size_t)(n0 + row) * DD + d], s);
        }
        if (t < 16) {
            float c = cnt_s[0][t] + cnt_s[1][t] + cnt_s[2][t] + cnt_s[3][t];
            atomicAdd(&pcnt[n0 + t], c);
        }
    }

    // ---- scoring: register-K, R9 proven form --------------------------------
    const float4* kr = reinterpret_cast<const float4*>(kmat + ((size_t)b * LL + l) * DD);
    float4 kreg[16];
    #pragma unroll
    for (int i = 0; i < 16; ++i) kreg[i] = kr[i];

    const int qb = __builtin_amdgcn_readfirstlane(n0 * DD);
    #pragma unroll
    for (int p = 0; p < 16; ++p) {
        const float4* qp = reinterpret_cast<const float4*>(q + qb + p * DD);
        float ax = 0.f, ay = 0.f, az = 0.f, aw = 0.f;
        #pragma unroll
        for (int i = 0; i < 16; ++i) {
            float4 qv = qp[i];                       // wave-uniform -> s_load
            ax = fmaf(qv.x, kreg[i].x, ax);
            ay = fmaf(qv.y, kreg[i].y, ay);
            az = fmaf(qv.z, kreg[i].z, az);
            aw = fmaf(qv.w, kreg[i].w, aw);
        }
        float acc = ax + ay + az + aw;
        ws_sc[(size_t)(n0 + p) * LL + l] = mreg[p] ? acc * 0.125f : -FLT_MAX;
    }
}

// ============================================================================
// K2: per-wave exact radix top-32 — VERBATIM R10 (control).
// ============================================================================
__global__ __launch_bounds__(256, 3) void k_select(
    const float* __restrict__ vmat,
    const float* __restrict__ ws,
    const float* __restrict__ pcnt,
    float*       __restrict__ out)
{
    __shared__ unsigned int hist[4][256];
    __shared__ unsigned int selKey[4][KEEP];
    __shared__ int          selIdx[4][KEEP];
    __shared__ float        wsel[4][KEEP];
    __shared__ int          selCnt[4], eqCnt[4];

    const int t    = threadIdx.x;
    const int wave = t >> 6;
    const int lane = t & 63;
    const int row  = blockIdx.x * 4 + wave;
    const int b    = row / LQ;

    // ---- mean finalize: sum (atomic-accumulated) / clip(count,1) ------------
    float o = out[(size_t)row * DD + lane];
    {
        float cc = pcnt[row];
        if (cc < 1.f) cc = 1.f;
        o /= cc;
    }

    // ---- load row scores -> order-preserving uint keys (64 VGPRs) -----------
    unsigned int key[64];
    {
        const float4* sg = reinterpret_cast<const float4*>(ws) + (size_t)row * (LL / 4);
        #pragma unroll
        for (int i = 0; i < 16; ++i) {
            float4 f = sg[lane + 64 * i];
            float vals[4] = { f.x, f.y, f.z, f.w };
            #pragma unroll
            for (int c = 0; c < 4; ++c) {
                unsigned int u = __float_as_uint(vals[c]);
                key[4 * i + c] = ((int)u < 0) ? ~u : (u | 0x80000000u);
            }
        }
    }

    // ---- 4-pass radix select: exact 32nd-largest key + tie quota ------------
    unsigned int prefix = 0, quota = KEEP;
    #pragma unroll
    for (int pass = 0; pass < 4; ++pass) {
        const int shift = 24 - 8 * pass;
        const unsigned int hs = (pass == 0) ? 0u : (unsigned int)(32 - 8 * pass);
        reinterpret_cast<uint4*>(hist[wave])[lane] = make_uint4(0u, 0u, 0u, 0u);
        __asm__ volatile("s_waitcnt lgkmcnt(0)" ::: "memory");
        #pragma unroll
        for (int e = 0; e < 64; ++e) {
            bool act = (pass == 0) || ((key[e] >> hs) == prefix);
            if (act) atomicAdd(&hist[wave][(key[e] >> shift) & 255u], 1u);
        }
        __asm__ volatile("s_waitcnt lgkmcnt(0)" ::: "memory");
        uint4 h = reinterpret_cast<const uint4*>(hist[wave])[lane];
        unsigned int s4  = h.x + h.y + h.z + h.w;
        unsigned int suf = s4;
        #pragma unroll
        for (int off = 1; off < 64; off <<= 1) {
            unsigned int v = (unsigned int)__shfl_down((int)suf, off);
            if (lane + off < 64) suf += v;
        }
        unsigned int above = suf - s4;
        bool cond = (suf >= quota) && (above < quota);
        unsigned int Bq = 0, nq = 0;
        if (cond) {
            unsigned int hb[4] = { h.x, h.y, h.z, h.w };
            unsigned int run = above;
            int Bj = 0;
            #pragma unroll
            for (int j = 3; j >= 0; --j) {
                unsigned int nb = run + hb[j];
                if (nb >= quota) { Bj = j; break; }
                run = nb;
            }
            Bq = (unsigned int)(lane * 4 + Bj);
            nq = quota - run;
        }
        unsigned long long bal = __ballot(cond);
        int src = __ffsll(bal) - 1;
        Bq = (unsigned int)__shfl((int)Bq, src);
        nq = (unsigned int)__shfl((int)nq, src);
        prefix = (prefix << 8) | Bq;
        quota  = nq;
    }
    const unsigned int T = prefix;
    const bool take_eq = (T != MASKED_KEY);

    // ---- compact selected (val,idx) into LDS --------------------------------
    if (lane < KEEP) { wsel[wave][lane] = 0.f; selIdx[wave][lane] = 0; }
    if (lane == 0)   { selCnt[wave] = 0; eqCnt[wave] = 0; }
    __asm__ volatile("s_waitcnt lgkmcnt(0)" ::: "memory");
    #pragma unroll
    for (int e = 0; e < 64; ++e) {
        unsigned int k = key[e];
        if (k > T) {
            int slot = atomicAdd(&selCnt[wave], 1);
            selKey[wave][slot] = k;
            selIdx[wave][slot] = 256 * (e >> 2) + 4 * lane + (e & 3);
        } else if (take_eq && k == T) {
            int t2 = atomicAdd(&eqCnt[wave], 1);
            if (t2 < (int)quota) {
                int slot = atomicAdd(&selCnt[wave], 1);
                selKey[wave][slot] = k;
                selIdx[wave][slot] = 256 * (e >> 2) + 4 * lane + (e & 3);
            }
        }
    }
    __asm__ volatile("s_waitcnt lgkmcnt(0)" ::: "memory");
    const int S = selCnt[wave];

    // ---- softmax over selected + padded static gather -----------------------
    if (S > 0) {
        float vj = -FLT_MAX;
        if (lane < S) {
            unsigned int kk = selKey[wave][lane];
            unsigned int u = (kk & 0x80000000u) ? (kk ^ 0x80000000u) : ~kk;
            vj = __uint_as_float(u);
        }
        float mx = vj;
        #pragma unroll
        for (int off = 1; off < 64; off <<= 1) mx = fmaxf(mx, __shfl_xor(mx, off));
        float e = (lane < S) ? expf(vj - mx) : 0.f;
        float sum = e;
        #pragma unroll
        for (int off = 1; off < 64; off <<= 1) sum += __shfl_xor(sum, off);
        if (lane < S) wsel[wave][lane] = e / sum;
        __asm__ volatile("s_waitcnt lgkmcnt(0)" ::: "memory");
        const float* vb = vmat + (size_t)b * LL * DD + lane;
        #pragma unroll
        for (int j = 0; j < KEEP; ++j) {
            float wj = wsel[wave][j];
            int   ij = selIdx[wave][j];
            o += wj * vb[(size_t)ij * DD];
        }
    }
    out[(size_t)row * DD + lane] = o;
}

// ============================================================================
// Fallback (proven round-1 monolith) in case ws_size < WS_TOTAL*4.
// ============================================================================
#define QT   2
#define NT   256
#define NTILES (LL / NT)

__global__ __launch_bounds__(NT, 4) void ga_fused_fb(
    const float* __restrict__ q, const float* __restrict__ kmat,
    const float* __restrict__ vmat, const int* __restrict__ mask,
    float* __restrict__ out)
{
    __shared__ float sc[QT][LL];
    __shared__ float q_s[QT][DD];
    __shared__ unsigned long long mbits[QT][LL / 64];
    __shared__ float redv[4][QT][DD];
    __shared__ float mean_s[QT][DD];
    __shared__ int   count_s[QT];
    __shared__ int   sel_idx[QT][KEEP];
    __shared__ float sel_val[QT][KEEP];
    __shared__ int   sel_cnt[QT];
    __shared__ float wred[4];
    __shared__ int   ired[4];
    __shared__ int   brk;
    __shared__ float wgt[QT][KEEP];

    const int t = threadIdx.x, wave = t >> 6, lane = t & 63;
    const int n0 = blockIdx.x * QT, b = n0 / LQ;

    if (t < QT) sel_cnt[t] = 0;
    if (t < QT * DD) q_s[t >> 6][t & 63] = q[(size_t)(n0 + (t >> 6)) * DD + (t & 63)];
    __syncthreads();

    const float4* q4_0 = reinterpret_cast<const float4*>(&q_s[0][0]);
    const float4* q4_1 = reinterpret_cast<const float4*>(&q_s[1][0]);
    for (int tile = 0; tile < NTILES; ++tile) {
        int l = tile * NT + t;
        const float4* kr = reinterpret_cast<const float4*>(kmat + (size_t)(b * LL + l) * DD);
        float d0 = 0.f, d1 = 0.f;
        #pragma unroll
        for (int i = 0; i < 16; ++i) {
            float4 kk = kr[i], qa = q4_0[i], qb = q4_1[i];
            d0 += kk.x * qa.x + kk.y * qa.y + kk.z * qa.z + kk.w * qa.w;
            d1 += kk.x * qb.x + kk.y * qb.y + kk.z * qb.z + kk.w * qb.w;
        }
        int mv0 = mask[(size_t)n0 * LL + l];
        int mv1 = mask[(size_t)(n0 + 1) * LL + l];
        unsigned long long b0 = __ballot(mv0 != 0);
        unsigned long long b1 = __ballot(mv1 != 0);
        if (lane == 0) { mbits[0][tile * 4 + wave] = b0; mbits[1][tile * 4 + wave] = b1; }
        sc[0][l] = mv0 ? d0 * 0.125f : -FLT_MAX;
        sc[1][l] = mv1 ? d1 * 0.125f : -FLT_MAX;
    }
    __syncthreads();

    if (wave < QT) {
        int c = (int)__popcll(mbits[wave][lane]);
        for (int off = 32; off >= 1; off >>= 1) c += __shfl_down(c, off);
        if (lane == 0) count_s[wave] = c;
    }
    {
        float acc0 = 0.f, acc1 = 0.f;
        const int g = wave, d = lane;
        for (int wi = 0; wi < LL / 64; ++wi) {
            unsigned long long w0 = mbits[0][wi], w1 = mbits[1][wi];
            const float* vp = vmat + (size_t)(b * LL + wi * 64 + g) * DD + d;
            #pragma unroll 4
            for (int ii = 0; ii < 16; ++ii) {
                int sh = g + 4 * ii;
                float vv = vp[(size_t)(4 * ii) * DD];
                if ((w0 >> sh) & 1ULL) acc0 += vv;
                if ((w1 >> sh) & 1ULL) acc1 += vv;
            }
        }
        redv[g][0][d] = acc0; redv[g][1][d] = acc1;
    }
    __syncthreads();
    if (t < QT * DD) {
        int qt = t >> 6, dd = t & 63;
        float s2 = redv[0][qt][dd] + redv[1][qt][dd] + redv[2][qt][dd] + redv[3][qt][dd];
        int c = count_s[qt]; if (c < 1) c = 1;
        mean_s[qt][dd] = s2 / (float)c;
    }
    __syncthreads();

    for (int qt = 0; qt < QT; ++qt) {
        for (int s = 0; s < KEEP; ++s) {
            float m = -FLT_MAX; int mi = LL;
            for (int j = 0; j < NTILES; ++j) {
                int l = j * NT + t;
                float val = sc[qt][l];
                if (val > m) { m = val; mi = l; }
            }
            for (int off = 32; off >= 1; off >>= 1) {
                float ov = __shfl_down(m, off);
                int   oi = __shfl_down(mi, off);
                if (ov > m || (ov == m && oi < mi)) { m = ov; mi = oi; }
            }
            if (lane == 0) { wred[wave] = m; ired[wave] = mi; }
            __syncthreads();
            if (t == 0) {
                float bv = wred[0]; int bi = ired[0];
                for (int w2 = 1; w2 < 4; ++w2) {
                    float ov = wred[w2]; int oi = ired[w2];
                    if (ov > bv || (ov == bv && oi < bi)) { bv = ov; bi = oi; }
                }
                if (bv > -FLT_MAX) {
                    sel_idx[qt][s] = bi; sel_val[qt][s] = bv; sel_cnt[qt] = s + 1;
                    sc[qt][bi] = -FLT_MAX; brk = 0;
                } else brk = 1;
            }
            __syncthreads();
            if (brk) break;
        }
    }

    if (wave < QT) {
        int qt = wave, S = sel_cnt[qt];
        if (S > 0) {
            float mx = sel_val[qt][0];
            float e = 0.f;
            if (lane < S) e = expf(sel_val[qt][lane] - mx);
            float ssum = e;
            for (int off = 32; off >= 1; off >>= 1) ssum += __shfl_xor(ssum, off);
            if (lane < S) wgt[qt][lane] = e / ssum;
        }
    }
    __syncthreads();
    if (wave < QT) {
        int qt = wave, S = sel_cnt[qt];
        float o = mean_s[qt][lane];
        for (int j = 0; j < S; ++j)
            o += wgt[qt][j] * vmat[(size_t)(b * LL + sel_idx[qt][j]) * DD + lane];
        out[(size_t)(n0 + qt) * DD + lane] = o;
    }
}

// ============================================================================
extern "C" void kernel_launch(void* const* d_in, const int* in_sizes, int n_in,
                              void* d_out, int out_size, void* d_ws, size_t ws_size,
                              hipStream_t stream) {
    const float* q    = (const float*)d_in[0];
    const float* kmat = (const float*)d_in[1];
    const float* vmat = (const float*)d_in[2];
    const int*   mask = (const int*)d_in[3];
    float* out = (float*)d_out;

    const size_t need = (size_t)WS_TOTAL * sizeof(float);   // 71.37 MB (== proven)
    if (ws_size >= need) {
        float* ws = (float*)d_ws;
        unsigned short* vt = (unsigned short*)(ws + WS_VT);
        float* pcnt = ws + WS_PC;
        // 3 graph nodes total (was 5): k_vt also zeroes out+pcnt.
        hipLaunchKernelGGL(k_vt, dim3(NB * 16), dim3(256), 0, stream,
                           vmat, vt, out, pcnt);
        hipLaunchKernelGGL(k_scores, dim3(4096), dim3(256), 0, stream,
                           q, kmat, mask, vt, ws, out, pcnt);
        hipLaunchKernelGGL(k_select, dim3(NROWS / 4), dim3(256), 0, stream,
                           vmat, ws, pcnt, out);
    } else {
        hipLaunchKernelGGL(ga_fused_fb, dim3(NROWS / QT), dim3(NT), 0, stream,
                           q, kmat, vmat, mask, out);
    }
}